// Round 18
// baseline (106.875 us; speedup 1.0000x reference)
//
#include <hip/hip_runtime.h>
#include <hip/hip_bf16.h>

#define NB 32
#define NN 1024
#define DINR 144

typedef __attribute__((ext_vector_type(4))) float f4;
typedef __attribute__((ext_vector_type(8))) short s8;

// ws float offsets
#define OFF_B0   (0u)                          // bf16 [32][1024][64]
#define OFF_B1   (1048576u)
#define OFF_S0   (2097152u)                    // f32 [32][32][1024]
#define OFF_UPA  (3145728u)                    // f32 [32][16][1024]
#define OFF_UPB  (3670016u)
#define OFF_GP   (4194304u)                    // f32 [32][ct:32][2][512]
#define OFF_NS   (5242880u)

static __device__ __forceinline__ unsigned short bf16u(float f) {
  __hip_bfloat16 h = __float2bfloat16(f);
  return *reinterpret_cast<unsigned short*>(&h);
}
static __device__ __forceinline__ float bfu2f(unsigned int u16) {
  unsigned int v = u16 << 16;
  return __uint_as_float(v);
}

// ---------------------------------------------------------------------------
// k_init  (unchanged from R16 — proven)
// ---------------------------------------------------------------------------
__global__ __launch_bounds__(256) void k_init(
    const float* __restrict__ x, const float* __restrict__ emb,
    unsigned short* __restrict__ Bt, float* __restrict__ Gp,
    float* __restrict__ S0, int* __restrict__ nstar)
{
  __shared__ union {
    unsigned int XT[NN * 8];
    struct {
      float xs[144 * 36];
      unsigned int Eb[64 * 16];
      unsigned short etr[32 * 72];
    } d;
  } sm;
  int t = threadIdx.x;
  if (blockIdx.x < 1024) {
    int b = blockIdx.x >> 5;
    int ct = blockIdx.x & 31;
    int n0 = ct * 32;
    const float* xb = x + (size_t)b * DINR * NN;
    for (int idx = t; idx < 144 * 32; idx += 256) {
      int row = idx >> 5, col = idx & 31;
      sm.d.xs[row * 36 + col] = xb[row * NN + n0 + col];
    }
    for (int e = t; e < 1024; e += 256) {
      int j = e >> 4, hp = e & 15;
      float f0 = emb[j * 32 + hp * 2];
      float f1 = emb[j * 32 + hp * 2 + 1];
      sm.d.Eb[j * 16 + hp] =
          (unsigned int)bf16u(f0) | ((unsigned int)bf16u(f1) << 16);
    }
    for (int e = t; e < 2048; e += 256) {
      int j = e >> 5, cat = e & 31;
      sm.d.etr[cat * 72 + j] = bf16u(emb[e]);
    }
    __syncthreads();
    int lane = t & 63, w = t >> 6;
    int r = lane & 15, q = lane >> 4;
    {
      s8 af = *reinterpret_cast<const s8*>(&sm.d.Eb[(w * 16 + r) * 16 + q * 4]);
      #pragma unroll
      for (int nt = 0; nt < 2; nt++) {
        union { s8 v; unsigned short u[8]; } B;
        #pragma unroll
        for (int e = 0; e < 8; e++)
          B.u[e] = bf16u(sm.d.xs[(48 + q * 8 + e) * 36 + nt * 16 + r]);
        f4 acc = {0.f, 0.f, 0.f, 0.f};
        acc = __builtin_amdgcn_mfma_f32_16x16x32_bf16(af, B.v, acc, 0, 0, 0);
        int n = n0 + nt * 16 + r;
        unsigned int p0 = (unsigned int)bf16u(acc[0]) | ((unsigned int)bf16u(acc[1]) << 16);
        unsigned int p1 = (unsigned int)bf16u(acc[2]) | ((unsigned int)bf16u(acc[3]) << 16);
        unsigned int* dst = reinterpret_cast<unsigned int*>(
            Bt + ((size_t)b * NN + n) * 64 + w * 16 + q * 4);
        dst[0] = p0; dst[1] = p1;
      }
    }
    {
      int mt = w & 1;
      int nt = w >> 1;
      f4 acc = {0.f, 0.f, 0.f, 0.f};
      #pragma unroll
      for (int kt = 0; kt < 2; kt++) {
        s8 ae = *reinterpret_cast<const s8*>(&sm.d.etr[(mt * 16 + r) * 72 + kt * 32 + q * 8]);
        union { s8 v; unsigned short u[8]; } Bx;
        #pragma unroll
        for (int e = 0; e < 8; e++)
          Bx.u[e] = bf16u(sm.d.xs[(80 + kt * 32 + q * 8 + e) * 36 + nt * 16 + r]);
        acc = __builtin_amdgcn_mfma_f32_16x16x32_bf16(ae, Bx.v, acc, 0, 0, 0);
      }
      #pragma unroll
      for (int reg = 0; reg < 4; reg++)
        S0[(size_t)b * 32 * NN + (size_t)(mt * 16 + q * 4 + reg) * NN + n0 + nt * 16 + r] = acc[reg];
    }
    __syncthreads();
    if (n0 + 32 > 1008) {
      for (int idx = t; idx < 80 * 16; idx += 256) {
        int row = idx >> 4, col = 16 + (idx & 15);
        sm.d.xs[row * 36 + col] = 0.f;
      }
    }
    __syncthreads();
    float* gp = Gp + ((size_t)(b * 32 + ct)) * 1024;
    for (int e = t; e < 1024; e += 256) {
      int mat = e >> 9, rr = (e >> 4) & 31, i = e & 15;
      const f4* xr = reinterpret_cast<const f4*>(&sm.d.xs[(16 + mat * 32 + rr) * 36]);
      const f4* xi = reinterpret_cast<const f4*>(&sm.d.xs[i * 36]);
      float s = 0.f;
      #pragma unroll
      for (int cq = 0; cq < 8; cq++) {
        f4 a = xr[cq], bq = xi[cq];
        s += a[0]*bq[0] + a[1]*bq[1] + a[2]*bq[2] + a[3]*bq[3];
      }
      gp[e] = s;
    }
  } else {
    int a = blockIdx.x - 1024;
    int b = a >> 4;
    int mg = a & 15;
    const float* xb = x + (size_t)b * DINR * NN;
    #pragma unroll
    for (int rep = 0; rep < 4; rep++) {
      int n = t + (rep << 8);
      unsigned int pk[8];
      #pragma unroll
      for (int h = 0; h < 8; h++) {
        unsigned int u0 = __float_as_uint(xb[(2*h) * NN + n]);
        unsigned int u1 = __float_as_uint(xb[(2*h+1) * NN + n]);
        pk[h] = (u0 >> 16) | (u1 & 0xFFFF0000u);
      }
      #pragma unroll
      for (int h = 0; h < 8; h++) sm.XT[n * 8 + h] = pk[h];
    }
    __syncthreads();
    int w = t >> 6;
    int lane = t & 63;
    int r = lane & 15;
    int g = lane >> 4;
    int mt = mg * 64 + w * 16;
    s8 zero8 = {0,0,0,0,0,0,0,0};
    s8 afrag = zero8;
    if (g < 2) afrag = *reinterpret_cast<const s8*>(&sm.XT[(mt + r) * 8 + g * 4]);
    float bestv[4];
    int besti[4];
    #pragma unroll
    for (int j = 0; j < 4; j++) { bestv[j] = -3.4e38f; besti[j] = 0x7FFFFFFF; }
    for (int nt = 0; nt < 63; nt++) {
      s8 bfrag = zero8;
      if (g < 2) bfrag = *reinterpret_cast<const s8*>(&sm.XT[(nt*16 + r) * 8 + g * 4]);
      f4 acc = {0.f, 0.f, 0.f, 0.f};
      acc = __builtin_amdgcn_mfma_f32_16x16x32_bf16(afrag, bfrag, acc, 0, 0, 0);
      int n = nt * 16 + r;
      #pragma unroll
      for (int j = 0; j < 4; j++) {
        float v = acc[j];
        bool better = (v > bestv[j]) || (v == bestv[j] && n < besti[j]);
        if (better) { bestv[j] = v; besti[j] = n; }
      }
    }
    #pragma unroll
    for (int s = 1; s < 16; s <<= 1) {
      #pragma unroll
      for (int j = 0; j < 4; j++) {
        float ov = __shfl_xor(bestv[j], s, 64);
        int   oi = __shfl_xor(besti[j], s, 64);
        bool better = (ov > bestv[j]) || (ov == bestv[j] && oi < besti[j]);
        if (better) { bestv[j] = ov; besti[j] = oi; }
      }
    }
    if (r == 0) {
      #pragma unroll
      for (int j = 0; j < 4; j++)
        nstar[b * NN + mt + g * 4 + j] = besti[j];
    }
  }
}

// ---------------------------------------------------------------------------
// k_upd (layer l, grid 512 = 32 b x 16 tiles, 256 thr):
//  in-block comb: Gs2/Gs3 = Σct Gp; Ucum = A2∘EG2 − α0∘EG3 − α1∘SUp1 − α2∘SUp2
//  V = E^T@Ucum -> Vs (bf16, in LDS);  then R16 upd body:
//  logits = S0 + sc*(V@X); softmax; [l==2: write out, done]
//  else: Ep=E@Ps; B-update bf16; Up chunk = w@X^T -> UpOut
// ---------------------------------------------------------------------------
__global__ __launch_bounds__(256) void k_upd(
    const float* __restrict__ x, const float* __restrict__ emb,
    const float* __restrict__ kpp, const float* __restrict__ alpha,
    const float* __restrict__ Gp, const float* __restrict__ S0,
    const int* __restrict__ nstar,
    const float* __restrict__ UpA, const float* __restrict__ UpB,
    const unsigned short* __restrict__ Bin, unsigned short* __restrict__ Bout,
    float* __restrict__ UpOut, int l, float* __restrict__ out)
{
  __shared__ float Gs2[512];
  __shared__ float Gs3[512];
  __shared__ float UcS[1024];
  __shared__ unsigned short Xt[64 * 24];   // X^T [col][i]
  __shared__ unsigned short Xb[16 * 72];   // X [i][col]
  __shared__ unsigned short Eb[64 * 40];   // E [j][cat]
  __shared__ unsigned short Vs[32 * 24];   // V bf16 [cat][i]
  __shared__ unsigned short Ps[64 * 40];   // p bf16 [col][cat]
  __shared__ unsigned short Wsh[64 * 72];  // w bf16 [j][col]
  int t = threadIdx.x;
  int b = blockIdx.x >> 4;
  int mt = blockIdx.x & 15;
  int n0 = mt * 64;
  int lane = t & 63, w = t >> 6;
  int r = lane & 15, q = lane >> 4;
  const float* xb = x + (size_t)b * DINR * NN;

  // ---- staging (X, E) ----
  for (int e = t; e < 1024; e += 256) {
    int i = e >> 6, col = e & 63;
    unsigned short v = bf16u(xb[i * NN + n0 + col]);
    Xb[i * 72 + col] = v;
    Xt[col * 24 + i] = v;
  }
  for (int e = t; e < 2048; e += 256) {
    int j = e >> 5, cat = e & 31;
    Eb[j * 40 + cat] = bf16u(emb[e]);
  }
  // ---- comb 1: Gram sums ----
  for (int e = t; e < 512; e += 256) {
    const float* p2 = Gp + (size_t)b * 32 * 1024 + e;
    float s2 = 0.f, s3 = 0.f;
    #pragma unroll 8
    for (int ct = 0; ct < 32; ct++) {
      s2 += p2[ct * 1024];
      s3 += p2[ct * 1024 + 512];
    }
    Gs2[e] = s2; Gs3[e] = s3;
  }
  __syncthreads();
  // ---- comb 2: Ucum ----
  for (int e = t; e < 1024; e += 256) {
    int j = e >> 4, i = e & 15;
    float a0 = alpha[j], a1 = alpha[64 + j], a2 = alpha[128 + j];
    const float* Er = emb + j * 32;
    float eg2 = 0.f, eg3 = 0.f;
    #pragma unroll
    for (int cat = 0; cat < 32; cat++) {
      float ev = Er[cat];
      eg2 = fmaf(ev, Gs2[cat * 16 + i], eg2);
      eg3 = fmaf(ev, Gs3[cat * 16 + i], eg3);
    }
    float acc;
    if (l == 0) {
      acc = a0 * (eg2 - eg3);
    } else {
      float sup1 = 0.f;
      const float* pa = UpA + (size_t)b * 16 * 1024 + e;
      #pragma unroll 8
      for (int ch = 0; ch < 16; ch++) sup1 += pa[ch * 1024];
      if (l == 1) {
        acc = (a0 + a1) * eg2 - a0 * eg3 - a1 * sup1;
      } else {
        float sup2 = 0.f;
        const float* pb = UpB + (size_t)b * 16 * 1024 + e;
        #pragma unroll 8
        for (int ch = 0; ch < 16; ch++) sup2 += pb[ch * 1024];
        acc = (a0 + a1 + a2) * eg2 - a0 * eg3 - a1 * sup1 - a2 * sup2;
      }
    }
    UcS[e] = acc;
  }
  __syncthreads();
  // ---- comb 3: V = E^T @ Ucum -> Vs (bf16) ----
  for (int e = t; e < 512; e += 256) {
    int cat = e >> 4, i = e & 15;
    float acc = 0.f;
    #pragma unroll
    for (int j = 0; j < 64; j++)
      acc = fmaf(emb[j * 32 + cat], UcS[j * 16 + i], acc);
    Vs[cat * 24 + i] = bf16u(acc);
  }
  __syncthreads();

  float sc = kpp[0] * (1.0f / 1008.0f);
  int mcol = n0 + w * 16 + r;
  s8 zero8 = {0, 0, 0, 0, 0, 0, 0, 0};

  // ---- logits = S0 + sc*(V@X) ----
  f4 sacc[2];
  {
    s8 bx = zero8;
    if (q < 2) bx = *reinterpret_cast<const s8*>(&Xt[(w * 16 + r) * 24 + q * 8]);
    #pragma unroll
    for (int ct = 0; ct < 2; ct++) {
      s8 av = zero8;
      if (q < 2) av = *reinterpret_cast<const s8*>(&Vs[(ct * 16 + r) * 24 + q * 8]);
      f4 z = {0.f, 0.f, 0.f, 0.f};
      f4 mm = __builtin_amdgcn_mfma_f32_16x16x32_bf16(av, bx, z, 0, 0, 0);
      #pragma unroll
      for (int reg = 0; reg < 4; reg++) {
        int cat = ct * 16 + q * 4 + reg;
        sacc[ct][reg] = S0[(size_t)b * 32 * NN + (size_t)cat * NN + mcol] + sc * mm[reg];
      }
    }
  }
  // ---- softmax ----
  float p[2][4];
  float mx = -3.4e38f;
  #pragma unroll
  for (int ct = 0; ct < 2; ct++)
    #pragma unroll
    for (int reg = 0; reg < 4; reg++) mx = fmaxf(mx, sacc[ct][reg]);
  mx = fmaxf(mx, __shfl_xor(mx, 16, 64));
  mx = fmaxf(mx, __shfl_xor(mx, 32, 64));
  float ss = 0.f;
  #pragma unroll
  for (int ct = 0; ct < 2; ct++)
    #pragma unroll
    for (int reg = 0; reg < 4; reg++) {
      p[ct][reg] = __expf(sacc[ct][reg] - mx);
      ss += p[ct][reg];
    }
  ss += __shfl_xor(ss, 16, 64);
  ss += __shfl_xor(ss, 32, 64);
  float inv = 1.0f / ss;
  #pragma unroll
  for (int ct = 0; ct < 2; ct++)
    #pragma unroll
    for (int reg = 0; reg < 4; reg++) p[ct][reg] *= inv;

  if (l == 2) {
    float* lo = out + ((size_t)b * NN + mcol) * 32;
    float* po = lo + (size_t)NB * NN * 32;
    #pragma unroll
    for (int ct = 0; ct < 2; ct++) {
      f4 vl = {sacc[ct][0], sacc[ct][1], sacc[ct][2], sacc[ct][3]};
      f4 vp = {p[ct][0], p[ct][1], p[ct][2], p[ct][3]};
      *reinterpret_cast<f4*>(lo + ct * 16 + q * 4) = vl;
      *reinterpret_cast<f4*>(po + ct * 16 + q * 4) = vp;
    }
    return;
  }

  // ---- p -> Ps (wave-local) ----
  #pragma unroll
  for (int ct = 0; ct < 2; ct++) {
    unsigned int u0 = (unsigned int)bf16u(p[ct][0]) | ((unsigned int)bf16u(p[ct][1]) << 16);
    unsigned int u1 = (unsigned int)bf16u(p[ct][2]) | ((unsigned int)bf16u(p[ct][3]) << 16);
    unsigned int base = (w * 16 + r) * 40 + ct * 16 + q * 4;
    *reinterpret_cast<unsigned int*>(&Ps[base]) = u0;
    *reinterpret_cast<unsigned int*>(&Ps[base + 2]) = u1;
  }
  // ---- GEMM3: Ep = Eb @ Ps ----
  f4 eacc[4];
  {
    s8 bp = *reinterpret_cast<const s8*>(&Ps[(w * 16 + r) * 40 + q * 8]);
    #pragma unroll
    for (int jt = 0; jt < 4; jt++) {
      s8 ae = *reinterpret_cast<const s8*>(&Eb[(jt * 16 + r) * 40 + q * 8]);
      f4 z = {0.f, 0.f, 0.f, 0.f};
      eacc[jt] = __builtin_amdgcn_mfma_f32_16x16x32_bf16(ae, bp, z, 0, 0, 0);
    }
  }
  // ---- B update (bf16, col-major [n][64]) ----
  int nst = nstar[b * NN + mcol];
  float vv[4][4];
  {
    const unsigned int* BC = reinterpret_cast<const unsigned int*>(
        Bin + ((size_t)b * NN + mcol) * 64);
    const unsigned int* BG = reinterpret_cast<const unsigned int*>(
        Bin + ((size_t)b * NN + nst) * 64);
    unsigned int* BO = reinterpret_cast<unsigned int*>(
        Bout + ((size_t)b * NN + mcol) * 64);
    const float invM = 1.0f / 1008.0f;
    #pragma unroll
    for (int jt = 0; jt < 4; jt++) {
      unsigned int c0 = BC[jt * 8 + q * 2], c1 = BC[jt * 8 + q * 2 + 1];
      unsigned int g0 = BG[jt * 8 + q * 2], g1 = BG[jt * 8 + q * 2 + 1];
      float bc[4] = { bfu2f(c0 & 0xFFFFu), bfu2f(c0 >> 16),
                      bfu2f(c1 & 0xFFFFu), bfu2f(c1 >> 16) };
      float bg[4] = { bfu2f(g0 & 0xFFFFu), bfu2f(g0 >> 16),
                      bfu2f(g1 & 0xFFFFu), bfu2f(g1 >> 16) };
      float vo[4];
      #pragma unroll
      for (int reg = 0; reg < 4; reg++) {
        vo[reg] = bc[reg] - bg[reg] * invM + eacc[jt][reg];
        vv[jt][reg] = vo[reg];
      }
      BO[jt * 8 + q * 2]     = (unsigned int)bf16u(vo[0]) | ((unsigned int)bf16u(vo[1]) << 16);
      BO[jt * 8 + q * 2 + 1] = (unsigned int)bf16u(vo[2]) | ((unsigned int)bf16u(vo[3]) << 16);
    }
  }
  // ---- w -> Wsh (masked) ----
  {
    bool live = (mcol < 1008);
    #pragma unroll
    for (int jt = 0; jt < 4; jt++)
      #pragma unroll
      for (int reg = 0; reg < 4; reg++)
        Wsh[(jt * 16 + q * 4 + reg) * 72 + (w * 16 + r)] =
            live ? bf16u(vv[jt][reg]) : (unsigned short)0;
  }
  __syncthreads();
  // ---- GEMM4: Up chunk = w @ X^T ----
  {
    f4 uacc = {0.f, 0.f, 0.f, 0.f};
    #pragma unroll
    for (int kt = 0; kt < 2; kt++) {
      s8 aw = *reinterpret_cast<const s8*>(&Wsh[(w * 16 + r) * 72 + kt * 32 + q * 8]);
      s8 bxx = *reinterpret_cast<const s8*>(&Xb[r * 72 + kt * 32 + q * 8]);
      uacc = __builtin_amdgcn_mfma_f32_16x16x32_bf16(aw, bxx, uacc, 0, 0, 0);
    }
    float* upb = UpOut + ((size_t)(b * 16 + mt)) * 1024;
    #pragma unroll
    for (int reg = 0; reg < 4; reg++)
      upb[(w * 16 + q * 4 + reg) * 16 + r] = uacc[reg];
  }
}

extern "C" void kernel_launch(void* const* d_in, const int* in_sizes, int n_in,
                              void* d_out, int out_size, void* d_ws, size_t ws_size,
                              hipStream_t stream)
{
  const float* x     = (const float*)d_in[0];
  const float* alpha = (const float*)d_in[1];
  const float* kp    = (const float*)d_in[2];
  const float* emb   = (const float*)d_in[3];
  float* ws = (float*)d_ws;
  unsigned short* B0u = (unsigned short*)(ws + OFF_B0);
  unsigned short* B1u = (unsigned short*)(ws + OFF_B1);
  float* S0   = ws + OFF_S0;
  float* UpA  = ws + OFF_UPA;
  float* UpB  = ws + OFF_UPB;
  float* Gp   = ws + OFF_GP;
  int*   ns   = (int*)(ws + OFF_NS);
  float* out  = (float*)d_out;

  k_init<<<1536, 256, 0, stream>>>(x, emb, B0u, Gp, S0, ns);
  // layer 0: B0->B1, write UpA
  k_upd<<<512, 256, 0, stream>>>(x, emb, kp, alpha, Gp, S0, ns,
                                 UpA, UpB, B0u, B1u, UpA, 0, out);
  // layer 1: B1->B0, read UpA, write UpB
  k_upd<<<512, 256, 0, stream>>>(x, emb, kp, alpha, Gp, S0, ns,
                                 UpA, UpB, B1u, B0u, UpB, 1, out);
  // layer 2 (last): read UpA+UpB, write out
  k_upd<<<512, 256, 0, stream>>>(x, emb, kp, alpha, Gp, S0, ns,
                                 UpA, UpB, B0u, B1u, UpA, 2, out);
}

// Round 19
// 75.657 us; speedup vs baseline: 1.4126x; 1.4126x over previous
//
#include <hip/hip_runtime.h>
#include <hip/hip_bf16.h>

#define NB 32
#define NN 1024
#define DINR 144

typedef __attribute__((ext_vector_type(4))) float f4;
typedef __attribute__((ext_vector_type(8))) short s8;

// ws float offsets
#define OFF_B0   (0u)                          // bf16 [32][1024][64]
#define OFF_B1   (1048576u)
#define OFF_S0   (2097152u)                    // f32 [32][32][1024]
#define OFF_GP   (3145728u)                    // f32 [32][ct:32][2][512]
#define OFF_VB   (4194304u)                    // f32 [32][3][512]
#define OFF_WPA  (4456448u)                    // f32 [32][16][512]
#define OFF_WPB  (4718592u)
#define OFF_W1S  (4980736u)                    // f32 [32][512]
#define OFF_NS   (4997120u)

static __device__ __forceinline__ unsigned short bf16u(float f) {
  __hip_bfloat16 h = __float2bfloat16(f);
  return *reinterpret_cast<unsigned short*>(&h);
}
static __device__ __forceinline__ float bfu2f(unsigned int u16) {
  unsigned int v = u16 << 16;
  return __uint_as_float(v);
}

// ---------------------------------------------------------------------------
// k_init  (R16-proven, unchanged)
// ---------------------------------------------------------------------------
__global__ __launch_bounds__(256) void k_init(
    const float* __restrict__ x, const float* __restrict__ emb,
    unsigned short* __restrict__ Bt, float* __restrict__ Gp,
    float* __restrict__ S0, int* __restrict__ nstar)
{
  __shared__ union {
    unsigned int XT[NN * 8];
    struct {
      float xs[144 * 36];
      unsigned int Eb[64 * 16];
      unsigned short etr[32 * 72];
    } d;
  } sm;
  int t = threadIdx.x;
  if (blockIdx.x < 1024) {
    int b = blockIdx.x >> 5;
    int ct = blockIdx.x & 31;
    int n0 = ct * 32;
    const float* xb = x + (size_t)b * DINR * NN;
    for (int idx = t; idx < 144 * 32; idx += 256) {
      int row = idx >> 5, col = idx & 31;
      sm.d.xs[row * 36 + col] = xb[row * NN + n0 + col];
    }
    for (int e = t; e < 1024; e += 256) {
      int j = e >> 4, hp = e & 15;
      float f0 = emb[j * 32 + hp * 2];
      float f1 = emb[j * 32 + hp * 2 + 1];
      sm.d.Eb[j * 16 + hp] =
          (unsigned int)bf16u(f0) | ((unsigned int)bf16u(f1) << 16);
    }
    for (int e = t; e < 2048; e += 256) {
      int j = e >> 5, cat = e & 31;
      sm.d.etr[cat * 72 + j] = bf16u(emb[e]);
    }
    __syncthreads();
    int lane = t & 63, w = t >> 6;
    int r = lane & 15, q = lane >> 4;
    {
      s8 af = *reinterpret_cast<const s8*>(&sm.d.Eb[(w * 16 + r) * 16 + q * 4]);
      #pragma unroll
      for (int nt = 0; nt < 2; nt++) {
        union { s8 v; unsigned short u[8]; } B;
        #pragma unroll
        for (int e = 0; e < 8; e++)
          B.u[e] = bf16u(sm.d.xs[(48 + q * 8 + e) * 36 + nt * 16 + r]);
        f4 acc = {0.f, 0.f, 0.f, 0.f};
        acc = __builtin_amdgcn_mfma_f32_16x16x32_bf16(af, B.v, acc, 0, 0, 0);
        int n = n0 + nt * 16 + r;
        unsigned int p0 = (unsigned int)bf16u(acc[0]) | ((unsigned int)bf16u(acc[1]) << 16);
        unsigned int p1 = (unsigned int)bf16u(acc[2]) | ((unsigned int)bf16u(acc[3]) << 16);
        unsigned int* dst = reinterpret_cast<unsigned int*>(
            Bt + ((size_t)b * NN + n) * 64 + w * 16 + q * 4);
        dst[0] = p0; dst[1] = p1;
      }
    }
    {
      int mt = w & 1;
      int nt = w >> 1;
      f4 acc = {0.f, 0.f, 0.f, 0.f};
      #pragma unroll
      for (int kt = 0; kt < 2; kt++) {
        s8 ae = *reinterpret_cast<const s8*>(&sm.d.etr[(mt * 16 + r) * 72 + kt * 32 + q * 8]);
        union { s8 v; unsigned short u[8]; } Bx;
        #pragma unroll
        for (int e = 0; e < 8; e++)
          Bx.u[e] = bf16u(sm.d.xs[(80 + kt * 32 + q * 8 + e) * 36 + nt * 16 + r]);
        acc = __builtin_amdgcn_mfma_f32_16x16x32_bf16(ae, Bx.v, acc, 0, 0, 0);
      }
      #pragma unroll
      for (int reg = 0; reg < 4; reg++)
        S0[(size_t)b * 32 * NN + (size_t)(mt * 16 + q * 4 + reg) * NN + n0 + nt * 16 + r] = acc[reg];
    }
    __syncthreads();
    if (n0 + 32 > 1008) {
      for (int idx = t; idx < 80 * 16; idx += 256) {
        int row = idx >> 4, col = 16 + (idx & 15);
        sm.d.xs[row * 36 + col] = 0.f;
      }
    }
    __syncthreads();
    float* gp = Gp + ((size_t)(b * 32 + ct)) * 1024;
    for (int e = t; e < 1024; e += 256) {
      int mat = e >> 9, rr = (e >> 4) & 31, i = e & 15;
      const f4* xr = reinterpret_cast<const f4*>(&sm.d.xs[(16 + mat * 32 + rr) * 36]);
      const f4* xi = reinterpret_cast<const f4*>(&sm.d.xs[i * 36]);
      float s = 0.f;
      #pragma unroll
      for (int cq = 0; cq < 8; cq++) {
        f4 a = xr[cq], bq = xi[cq];
        s += a[0]*bq[0] + a[1]*bq[1] + a[2]*bq[2] + a[3]*bq[3];
      }
      gp[e] = s;
    }
  } else {
    int a = blockIdx.x - 1024;
    int b = a >> 4;
    int mg = a & 15;
    const float* xb = x + (size_t)b * DINR * NN;
    #pragma unroll
    for (int rep = 0; rep < 4; rep++) {
      int n = t + (rep << 8);
      unsigned int pk[8];
      #pragma unroll
      for (int h = 0; h < 8; h++) {
        unsigned int u0 = __float_as_uint(xb[(2*h) * NN + n]);
        unsigned int u1 = __float_as_uint(xb[(2*h+1) * NN + n]);
        pk[h] = (u0 >> 16) | (u1 & 0xFFFF0000u);
      }
      #pragma unroll
      for (int h = 0; h < 8; h++) sm.XT[n * 8 + h] = pk[h];
    }
    __syncthreads();
    int w = t >> 6;
    int lane = t & 63;
    int r = lane & 15;
    int g = lane >> 4;
    int mt = mg * 64 + w * 16;
    s8 zero8 = {0,0,0,0,0,0,0,0};
    s8 afrag = zero8;
    if (g < 2) afrag = *reinterpret_cast<const s8*>(&sm.XT[(mt + r) * 8 + g * 4]);
    float bestv[4];
    int besti[4];
    #pragma unroll
    for (int j = 0; j < 4; j++) { bestv[j] = -3.4e38f; besti[j] = 0x7FFFFFFF; }
    for (int nt = 0; nt < 63; nt++) {
      s8 bfrag = zero8;
      if (g < 2) bfrag = *reinterpret_cast<const s8*>(&sm.XT[(nt*16 + r) * 8 + g * 4]);
      f4 acc = {0.f, 0.f, 0.f, 0.f};
      acc = __builtin_amdgcn_mfma_f32_16x16x32_bf16(afrag, bfrag, acc, 0, 0, 0);
      int n = nt * 16 + r;
      #pragma unroll
      for (int j = 0; j < 4; j++) {
        float v = acc[j];
        bool better = (v > bestv[j]) || (v == bestv[j] && n < besti[j]);
        if (better) { bestv[j] = v; besti[j] = n; }
      }
    }
    #pragma unroll
    for (int s = 1; s < 16; s <<= 1) {
      #pragma unroll
      for (int j = 0; j < 4; j++) {
        float ov = __shfl_xor(bestv[j], s, 64);
        int   oi = __shfl_xor(besti[j], s, 64);
        bool better = (ov > bestv[j]) || (ov == bestv[j] && oi < besti[j]);
        if (better) { bestv[j] = ov; besti[j] = oi; }
      }
    }
    if (r == 0) {
      #pragma unroll
      for (int j = 0; j < 4; j++)
        nstar[b * NN + mt + g * 4 + j] = besti[j];
    }
  }
}

// ---------------------------------------------------------------------------
// k_gram (32 blocks, 1 per batch): G2/G3 = Σct Gp; EG2/EG3 = E@G;
//   VBase_l = E^T @ (A_l∘EG2 − α0∘EG3), l = 0..2, A_l = Σ_{k<=l} α_k
// ---------------------------------------------------------------------------
__global__ __launch_bounds__(256) void k_gram(
    const float* __restrict__ Gp, const float* __restrict__ emb,
    const float* __restrict__ alpha, float* __restrict__ VBase)
{
  __shared__ float G2[512];
  __shared__ float G3[512];
  __shared__ float EG2s[1024];
  __shared__ float EG3s[1024];
  int b = blockIdx.x;
  int t = threadIdx.x;
  for (int e = t; e < 512; e += 256) {
    const float* p2 = Gp + (size_t)b * 32 * 1024 + e;
    float s2 = 0.f, s3 = 0.f;
    #pragma unroll 8
    for (int ct = 0; ct < 32; ct++) {
      s2 += p2[ct * 1024];
      s3 += p2[ct * 1024 + 512];
    }
    G2[e] = s2; G3[e] = s3;
  }
  __syncthreads();
  for (int e = t; e < 1024; e += 256) {
    int j = e >> 4, i = e & 15;
    const float* Er = emb + j * 32;
    float eg2 = 0.f, eg3 = 0.f;
    #pragma unroll
    for (int cat = 0; cat < 32; cat++) {
      float ev = Er[cat];
      eg2 = fmaf(ev, G2[cat * 16 + i], eg2);
      eg3 = fmaf(ev, G3[cat * 16 + i], eg3);
    }
    EG2s[e] = eg2; EG3s[e] = eg3;
  }
  __syncthreads();
  #pragma unroll
  for (int l = 0; l < 3; l++) {
    for (int e = t; e < 512; e += 256) {
      int cat = e >> 4, i = e & 15;
      float acc = 0.f;
      for (int j = 0; j < 64; j++) {
        float a0 = alpha[j];
        float Al = a0;
        if (l >= 1) Al += alpha[64 + j];
        if (l >= 2) Al += alpha[128 + j];
        float u = Al * EG2s[j * 16 + i] - a0 * EG3s[j * 16 + i];
        acc = fmaf(emb[j * 32 + cat], u, acc);
      }
      VBase[(size_t)b * 1536 + l * 512 + e] = acc;
    }
  }
}

// ---------------------------------------------------------------------------
// k_upd (layer l, grid 512 = 32 b x 16 tiles, 256 thr):
//  comb-lite: V = VBase_l − [l=1: ΣWpA; l=2: W1sum + ΣWpB] -> Vs (bf16)
//  logits = S0 + sc*(V@X); softmax; [l==2: out, done]
//  else: Ep=E@Ps; B-update bf16; uacc = w@X^T;
//        Wchunk = E^T@(α_{l+1}∘uacc) -> WpOut;  [l==1: mt==0 writes W1sum]
// ---------------------------------------------------------------------------
__global__ __launch_bounds__(256) void k_upd(
    const float* __restrict__ x, const float* __restrict__ emb,
    const float* __restrict__ kpp, const float* __restrict__ alphaN,
    const float* __restrict__ VBase, const float* __restrict__ S0,
    const int* __restrict__ nstar,
    const float* __restrict__ WpIn, float* __restrict__ W1sum,
    const unsigned short* __restrict__ Bin, unsigned short* __restrict__ Bout,
    float* __restrict__ WpOut, int l, float* __restrict__ out)
{
  __shared__ unsigned short Xt[64 * 24];   // X^T [col][i]
  __shared__ unsigned short Xb[16 * 72];   // X [i][col]
  __shared__ unsigned short Eb[64 * 40];   // E [j][cat]
  __shared__ unsigned short Et[32 * 72];   // E^T [cat][j]
  __shared__ unsigned short Vs[32 * 24];   // V bf16 [cat][i]
  __shared__ unsigned short Ps[64 * 40];   // p bf16 [col][cat]
  __shared__ unsigned short Wsh[64 * 72];  // w bf16 [j][col]
  __shared__ float Ups[64 * 18];           // alpha-scaled Up chunk [j][i]
  int t = threadIdx.x;
  int b = blockIdx.x >> 4;
  int mt = blockIdx.x & 15;
  int n0 = mt * 64;
  int lane = t & 63, w = t >> 6;
  int r = lane & 15, q = lane >> 4;
  const float* xb = x + (size_t)b * DINR * NN;

  // ---- staging (X, E, E^T) ----
  for (int e = t; e < 1024; e += 256) {
    int i = e >> 6, col = e & 63;
    unsigned short v = bf16u(xb[i * NN + n0 + col]);
    Xb[i * 72 + col] = v;
    Xt[col * 24 + i] = v;
  }
  for (int e = t; e < 2048; e += 256) {
    int j = e >> 5, cat = e & 31;
    unsigned short v = bf16u(emb[e]);
    Eb[j * 40 + cat] = v;
    Et[cat * 72 + j] = v;
  }
  // ---- comb-lite: V ----
  for (int e = t; e < 512; e += 256) {
    float acc = VBase[(size_t)b * 1536 + l * 512 + e];
    if (l == 1) {
      const float* pw = WpIn + (size_t)b * 16 * 512 + e;
      float s1 = 0.f;
      #pragma unroll 8
      for (int ch = 0; ch < 16; ch++) s1 += pw[ch * 512];
      if (mt == 0) W1sum[(size_t)b * 512 + e] = s1;
      acc -= s1;
    } else if (l == 2) {
      acc -= W1sum[(size_t)b * 512 + e];
      const float* pw = WpIn + (size_t)b * 16 * 512 + e;
      float s2 = 0.f;
      #pragma unroll 8
      for (int ch = 0; ch < 16; ch++) s2 += pw[ch * 512];
      acc -= s2;
    }
    Vs[(e >> 4) * 24 + (e & 15)] = bf16u(acc);
  }
  __syncthreads();

  float sc = kpp[0] * (1.0f / 1008.0f);
  int mcol = n0 + w * 16 + r;
  s8 zero8 = {0, 0, 0, 0, 0, 0, 0, 0};

  // ---- logits = S0 + sc*(V@X) ----
  f4 sacc[2];
  {
    s8 bx = zero8;
    if (q < 2) bx = *reinterpret_cast<const s8*>(&Xt[(w * 16 + r) * 24 + q * 8]);
    #pragma unroll
    for (int ct = 0; ct < 2; ct++) {
      s8 av = zero8;
      if (q < 2) av = *reinterpret_cast<const s8*>(&Vs[(ct * 16 + r) * 24 + q * 8]);
      f4 z = {0.f, 0.f, 0.f, 0.f};
      f4 mm = __builtin_amdgcn_mfma_f32_16x16x32_bf16(av, bx, z, 0, 0, 0);
      #pragma unroll
      for (int reg = 0; reg < 4; reg++) {
        int cat = ct * 16 + q * 4 + reg;
        sacc[ct][reg] = S0[(size_t)b * 32 * NN + (size_t)cat * NN + mcol] + sc * mm[reg];
      }
    }
  }
  // ---- softmax ----
  float p[2][4];
  float mx = -3.4e38f;
  #pragma unroll
  for (int ct = 0; ct < 2; ct++)
    #pragma unroll
    for (int reg = 0; reg < 4; reg++) mx = fmaxf(mx, sacc[ct][reg]);
  mx = fmaxf(mx, __shfl_xor(mx, 16, 64));
  mx = fmaxf(mx, __shfl_xor(mx, 32, 64));
  float ss = 0.f;
  #pragma unroll
  for (int ct = 0; ct < 2; ct++)
    #pragma unroll
    for (int reg = 0; reg < 4; reg++) {
      p[ct][reg] = __expf(sacc[ct][reg] - mx);
      ss += p[ct][reg];
    }
  ss += __shfl_xor(ss, 16, 64);
  ss += __shfl_xor(ss, 32, 64);
  float inv = 1.0f / ss;
  #pragma unroll
  for (int ct = 0; ct < 2; ct++)
    #pragma unroll
    for (int reg = 0; reg < 4; reg++) p[ct][reg] *= inv;

  if (l == 2) {
    float* lo = out + ((size_t)b * NN + mcol) * 32;
    float* po = lo + (size_t)NB * NN * 32;
    #pragma unroll
    for (int ct = 0; ct < 2; ct++) {
      f4 vl = {sacc[ct][0], sacc[ct][1], sacc[ct][2], sacc[ct][3]};
      f4 vp = {p[ct][0], p[ct][1], p[ct][2], p[ct][3]};
      *reinterpret_cast<f4*>(lo + ct * 16 + q * 4) = vl;
      *reinterpret_cast<f4*>(po + ct * 16 + q * 4) = vp;
    }
    return;
  }

  // ---- p -> Ps (wave-local) ----
  #pragma unroll
  for (int ct = 0; ct < 2; ct++) {
    unsigned int u0 = (unsigned int)bf16u(p[ct][0]) | ((unsigned int)bf16u(p[ct][1]) << 16);
    unsigned int u1 = (unsigned int)bf16u(p[ct][2]) | ((unsigned int)bf16u(p[ct][3]) << 16);
    unsigned int base = (w * 16 + r) * 40 + ct * 16 + q * 4;
    *reinterpret_cast<unsigned int*>(&Ps[base]) = u0;
    *reinterpret_cast<unsigned int*>(&Ps[base + 2]) = u1;
  }
  // ---- GEMM3: Ep = Eb @ Ps ----
  f4 eacc[4];
  {
    s8 bp = *reinterpret_cast<const s8*>(&Ps[(w * 16 + r) * 40 + q * 8]);
    #pragma unroll
    for (int jt = 0; jt < 4; jt++) {
      s8 ae = *reinterpret_cast<const s8*>(&Eb[(jt * 16 + r) * 40 + q * 8]);
      f4 z = {0.f, 0.f, 0.f, 0.f};
      eacc[jt] = __builtin_amdgcn_mfma_f32_16x16x32_bf16(ae, bp, z, 0, 0, 0);
    }
  }
  // ---- B update (bf16, col-major [n][64]) ----
  int nst = nstar[b * NN + mcol];
  float vv[4][4];
  {
    const unsigned int* BC = reinterpret_cast<const unsigned int*>(
        Bin + ((size_t)b * NN + mcol) * 64);
    const unsigned int* BG = reinterpret_cast<const unsigned int*>(
        Bin + ((size_t)b * NN + nst) * 64);
    unsigned int* BO = reinterpret_cast<unsigned int*>(
        Bout + ((size_t)b * NN + mcol) * 64);
    const float invM = 1.0f / 1008.0f;
    #pragma unroll
    for (int jt = 0; jt < 4; jt++) {
      unsigned int c0 = BC[jt * 8 + q * 2], c1 = BC[jt * 8 + q * 2 + 1];
      unsigned int g0 = BG[jt * 8 + q * 2], g1 = BG[jt * 8 + q * 2 + 1];
      float bc[4] = { bfu2f(c0 & 0xFFFFu), bfu2f(c0 >> 16),
                      bfu2f(c1 & 0xFFFFu), bfu2f(c1 >> 16) };
      float bg[4] = { bfu2f(g0 & 0xFFFFu), bfu2f(g0 >> 16),
                      bfu2f(g1 & 0xFFFFu), bfu2f(g1 >> 16) };
      float vo[4];
      #pragma unroll
      for (int reg = 0; reg < 4; reg++) {
        vo[reg] = bc[reg] - bg[reg] * invM + eacc[jt][reg];
        vv[jt][reg] = vo[reg];
      }
      BO[jt * 8 + q * 2]     = (unsigned int)bf16u(vo[0]) | ((unsigned int)bf16u(vo[1]) << 16);
      BO[jt * 8 + q * 2 + 1] = (unsigned int)bf16u(vo[2]) | ((unsigned int)bf16u(vo[3]) << 16);
    }
  }
  // ---- w -> Wsh (masked) ----
  {
    bool live = (mcol < 1008);
    #pragma unroll
    for (int jt = 0; jt < 4; jt++)
      #pragma unroll
      for (int reg = 0; reg < 4; reg++)
        Wsh[(jt * 16 + q * 4 + reg) * 72 + (w * 16 + r)] =
            live ? bf16u(vv[jt][reg]) : (unsigned short)0;
  }
  __syncthreads();
  // ---- GEMM4: uacc = w @ X^T (wave w -> j-tile w) ----
  f4 uacc = {0.f, 0.f, 0.f, 0.f};
  #pragma unroll
  for (int kt = 0; kt < 2; kt++) {
    s8 aw = *reinterpret_cast<const s8*>(&Wsh[(w * 16 + r) * 72 + kt * 32 + q * 8]);
    s8 bxx = *reinterpret_cast<const s8*>(&Xb[r * 72 + kt * 32 + q * 8]);
    uacc = __builtin_amdgcn_mfma_f32_16x16x32_bf16(aw, bxx, uacc, 0, 0, 0);
  }
  // ---- stage alpha-scaled Up chunk ----
  #pragma unroll
  for (int reg = 0; reg < 4; reg++)
    Ups[(w * 16 + q * 4 + reg) * 18 + r] = alphaN[w * 16 + q * 4 + reg] * uacc[reg];
  __syncthreads();
  // ---- Wchunk = E^T @ (alphaN∘Up) (waves 0-1, cat tile = w) ----
  if (w < 2) {
    f4 wacc = {0.f, 0.f, 0.f, 0.f};
    #pragma unroll
    for (int kt = 0; kt < 2; kt++) {
      s8 ae = *reinterpret_cast<const s8*>(&Et[(w * 16 + r) * 72 + kt * 32 + q * 8]);
      union { s8 v; unsigned short u[8]; } Bu;
      #pragma unroll
      for (int e = 0; e < 8; e++)
        Bu.u[e] = bf16u(Ups[(kt * 32 + q * 8 + e) * 18 + r]);
      wacc = __builtin_amdgcn_mfma_f32_16x16x32_bf16(ae, Bu.v, wacc, 0, 0, 0);
    }
    float* wp = WpOut + ((size_t)(b * 16 + mt)) * 512;
    #pragma unroll
    for (int reg = 0; reg < 4; reg++)
      wp[(w * 16 + q * 4 + reg) * 16 + r] = wacc[reg];
  }
}

extern "C" void kernel_launch(void* const* d_in, const int* in_sizes, int n_in,
                              void* d_out, int out_size, void* d_ws, size_t ws_size,
                              hipStream_t stream)
{
  const float* x     = (const float*)d_in[0];
  const float* alpha = (const float*)d_in[1];
  const float* kp    = (const float*)d_in[2];
  const float* emb   = (const float*)d_in[3];
  float* ws = (float*)d_ws;
  unsigned short* B0u = (unsigned short*)(ws + OFF_B0);
  unsigned short* B1u = (unsigned short*)(ws + OFF_B1);
  float* S0   = ws + OFF_S0;
  float* Gp   = ws + OFF_GP;
  float* VB   = ws + OFF_VB;
  float* WpA  = ws + OFF_WPA;
  float* WpB  = ws + OFF_WPB;
  float* W1s  = ws + OFF_W1S;
  int*   ns   = (int*)(ws + OFF_NS);
  float* out  = (float*)d_out;

  k_init<<<1536, 256, 0, stream>>>(x, emb, B0u, Gp, S0, ns);
  k_gram<<<32, 256, 0, stream>>>(Gp, emb, alpha, VB);
  // layer 0: B0->B1, writes WpA (alpha1-scaled W chunks)
  k_upd<<<512, 256, 0, stream>>>(x, emb, kp, alpha + 64, VB, S0, ns,
                                 WpA, W1s, B0u, B1u, WpA, 0, out);
  // layer 1: B1->B0, reads WpA (W1), writes W1sum + WpB (alpha2-scaled)
  k_upd<<<512, 256, 0, stream>>>(x, emb, kp, alpha + 128, VB, S0, ns,
                                 WpA, W1s, B1u, B0u, WpB, 1, out);
  // layer 2 (last): reads W1sum + WpB, writes out
  k_upd<<<512, 256, 0, stream>>>(x, emb, kp, alpha, VB, S0, ns,
                                 WpB, W1s, B0u, B1u, WpA, 2, out);
}

// Round 20
// 70.011 us; speedup vs baseline: 1.5265x; 1.0806x over previous
//
#include <hip/hip_runtime.h>
#include <hip/hip_bf16.h>

#define NB 32
#define NN 1024
#define DINR 144

typedef __attribute__((ext_vector_type(4))) float f4;
typedef __attribute__((ext_vector_type(8))) short s8;

// ws float offsets
#define OFF_B0   (0u)                          // bf16 [32][1024][64]
#define OFF_B1   (1048576u)
#define OFF_S0   (2097152u)                    // f32 [32][32][1024]
#define OFF_VB   (3145728u)                    // f32 [32][3][512]
#define OFF_WPA  (3194880u)                    // f32 [32][16][512]
#define OFF_WPB  (3457024u)
#define OFF_W1S  (3719168u)                    // f32 [32][512]
#define OFF_NS   (3735552u)

static __device__ __forceinline__ unsigned short bf16u(float f) {
  __hip_bfloat16 h = __float2bfloat16(f);
  return *reinterpret_cast<unsigned short*>(&h);
}
static __device__ __forceinline__ float bfu2f(unsigned int u16) {
  unsigned int v = u16 << 16;
  return __uint_as_float(v);
}

// ---------------------------------------------------------------------------
// k_init (grid 1568):
//  blocks [0,1024): b=blk>>5, ct=blk&31: stage x rows 48..144 + E;
//    B0 = E@x3 (bf16 col-major, MFMA); S0 = E^T@x[80:144] (f32, MFMA)
//  blocks [1024,1536): nstar = argmax_{n<1008} X[:,m]·X[:,n]  (bf16 MFMA)
//  blocks [1536,1568): per-batch Gram via MFMA (G2=x2@X^T, G3=x3@X^T,
//    K=1008 direct from global) + VBase_l = E^T@(A_l∘EG2 − α0∘EG3)
// ---------------------------------------------------------------------------
__global__ __launch_bounds__(256) void k_init(
    const float* __restrict__ x, const float* __restrict__ emb,
    const float* __restrict__ alpha,
    unsigned short* __restrict__ Bt, float* __restrict__ S0,
    float* __restrict__ VBase, int* __restrict__ nstar)
{
  __shared__ union {
    unsigned int XT[NN * 8];                   // 32768 B (argmax)
    struct {
      float xs[96 * 36];                       // 13824 B (rows 48..144)
      unsigned int Eb[64 * 16];                // 4096 B
      unsigned short etr[32 * 72];             // 4608 B
    } d;
    struct {
      float G[2][512];                         // 4096 B
      float EG2[1024];                         // 4096 B
      float EG3[1024];                         // 4096 B
    } g;
  } sm;
  int t = threadIdx.x;
  if (blockIdx.x < 1024) {
    int b = blockIdx.x >> 5;
    int ct = blockIdx.x & 31;
    int n0 = ct * 32;
    const float* xb = x + (size_t)b * DINR * NN;
    for (int idx = t; idx < 96 * 32; idx += 256) {
      int row = idx >> 5, col = idx & 31;
      sm.d.xs[row * 36 + col] = xb[(48 + row) * NN + n0 + col];
    }
    for (int e = t; e < 1024; e += 256) {
      int j = e >> 4, hp = e & 15;
      float f0 = emb[j * 32 + hp * 2];
      float f1 = emb[j * 32 + hp * 2 + 1];
      sm.d.Eb[j * 16 + hp] =
          (unsigned int)bf16u(f0) | ((unsigned int)bf16u(f1) << 16);
    }
    for (int e = t; e < 2048; e += 256) {
      int j = e >> 5, cat = e & 31;
      sm.d.etr[cat * 72 + j] = bf16u(emb[e]);
    }
    __syncthreads();
    int lane = t & 63, w = t >> 6;
    int r = lane & 15, q = lane >> 4;
    // B0 = E @ x3 (x3 = local rows 0..32)
    {
      s8 af = *reinterpret_cast<const s8*>(&sm.d.Eb[(w * 16 + r) * 16 + q * 4]);
      #pragma unroll
      for (int nt = 0; nt < 2; nt++) {
        union { s8 v; unsigned short u[8]; } B;
        #pragma unroll
        for (int e = 0; e < 8; e++)
          B.u[e] = bf16u(sm.d.xs[(q * 8 + e) * 36 + nt * 16 + r]);
        f4 acc = {0.f, 0.f, 0.f, 0.f};
        acc = __builtin_amdgcn_mfma_f32_16x16x32_bf16(af, B.v, acc, 0, 0, 0);
        int n = n0 + nt * 16 + r;
        unsigned int p0 = (unsigned int)bf16u(acc[0]) | ((unsigned int)bf16u(acc[1]) << 16);
        unsigned int p1 = (unsigned int)bf16u(acc[2]) | ((unsigned int)bf16u(acc[3]) << 16);
        unsigned int* dst = reinterpret_cast<unsigned int*>(
            Bt + ((size_t)b * NN + n) * 64 + w * 16 + q * 4);
        dst[0] = p0; dst[1] = p1;
      }
    }
    // S0 = E^T @ C0 (C0 = local rows 32..96)
    {
      int mt = w & 1;
      int nt = w >> 1;
      f4 acc = {0.f, 0.f, 0.f, 0.f};
      #pragma unroll
      for (int kt = 0; kt < 2; kt++) {
        s8 ae = *reinterpret_cast<const s8*>(&sm.d.etr[(mt * 16 + r) * 72 + kt * 32 + q * 8]);
        union { s8 v; unsigned short u[8]; } Bx;
        #pragma unroll
        for (int e = 0; e < 8; e++)
          Bx.u[e] = bf16u(sm.d.xs[(32 + kt * 32 + q * 8 + e) * 36 + nt * 16 + r]);
        acc = __builtin_amdgcn_mfma_f32_16x16x32_bf16(ae, Bx.v, acc, 0, 0, 0);
      }
      #pragma unroll
      for (int reg = 0; reg < 4; reg++)
        S0[(size_t)b * 32 * NN + (size_t)(mt * 16 + q * 4 + reg) * NN + n0 + nt * 16 + r] = acc[reg];
    }
  } else if (blockIdx.x < 1536) {
    int a = blockIdx.x - 1024;
    int b = a >> 4;
    int mg = a & 15;
    const float* xb = x + (size_t)b * DINR * NN;
    #pragma unroll
    for (int rep = 0; rep < 4; rep++) {
      int n = t + (rep << 8);
      unsigned int pk[8];
      #pragma unroll
      for (int h = 0; h < 8; h++) {
        unsigned int u0 = __float_as_uint(xb[(2*h) * NN + n]);
        unsigned int u1 = __float_as_uint(xb[(2*h+1) * NN + n]);
        pk[h] = (u0 >> 16) | (u1 & 0xFFFF0000u);
      }
      #pragma unroll
      for (int h = 0; h < 8; h++) sm.XT[n * 8 + h] = pk[h];
    }
    __syncthreads();
    int w = t >> 6;
    int lane = t & 63;
    int r = lane & 15;
    int g = lane >> 4;
    int mt = mg * 64 + w * 16;
    s8 zero8 = {0,0,0,0,0,0,0,0};
    s8 afrag = zero8;
    if (g < 2) afrag = *reinterpret_cast<const s8*>(&sm.XT[(mt + r) * 8 + g * 4]);
    float bestv[4];
    int besti[4];
    #pragma unroll
    for (int j = 0; j < 4; j++) { bestv[j] = -3.4e38f; besti[j] = 0x7FFFFFFF; }
    for (int nt = 0; nt < 63; nt++) {
      s8 bfrag = zero8;
      if (g < 2) bfrag = *reinterpret_cast<const s8*>(&sm.XT[(nt*16 + r) * 8 + g * 4]);
      f4 acc = {0.f, 0.f, 0.f, 0.f};
      acc = __builtin_amdgcn_mfma_f32_16x16x32_bf16(afrag, bfrag, acc, 0, 0, 0);
      int n = nt * 16 + r;
      #pragma unroll
      for (int j = 0; j < 4; j++) {
        float v = acc[j];
        bool better = (v > bestv[j]) || (v == bestv[j] && n < besti[j]);
        if (better) { bestv[j] = v; besti[j] = n; }
      }
    }
    #pragma unroll
    for (int s = 1; s < 16; s <<= 1) {
      #pragma unroll
      for (int j = 0; j < 4; j++) {
        float ov = __shfl_xor(bestv[j], s, 64);
        int   oi = __shfl_xor(besti[j], s, 64);
        bool better = (ov > bestv[j]) || (ov == bestv[j] && oi < besti[j]);
        if (better) { bestv[j] = ov; besti[j] = oi; }
      }
    }
    if (r == 0) {
      #pragma unroll
      for (int j = 0; j < 4; j++)
        nstar[b * NN + mt + g * 4 + j] = besti[j];
    }
  } else {
    // ---- Gram + VBase, one block per batch ----
    int b = blockIdx.x - 1536;
    const float* xb = x + (size_t)b * DINR * NN;
    int lane = t & 63, w = t >> 6;
    int r = lane & 15, q = lane >> 4;
    int mat = w >> 1, mt = w & 1;
    const float* arow = xb + (size_t)(16 + mat * 32 + mt * 16 + r) * NN;
    const float* brow = xb + (size_t)r * NN;
    f4 gacc = {0.f, 0.f, 0.f, 0.f};
    for (int kt = 0; kt < 32; kt++) {
      int k0 = kt * 32 + q * 8;
      union { s8 v; unsigned short u[8]; } A, B;
      if (kt < 31 || q < 2) {
        f4 a0 = *reinterpret_cast<const f4*>(arow + k0);
        f4 a1 = *reinterpret_cast<const f4*>(arow + k0 + 4);
        f4 b0 = *reinterpret_cast<const f4*>(brow + k0);
        f4 b1 = *reinterpret_cast<const f4*>(brow + k0 + 4);
        #pragma unroll
        for (int e = 0; e < 4; e++) {
          A.u[e] = bf16u(a0[e]); A.u[4 + e] = bf16u(a1[e]);
          B.u[e] = bf16u(b0[e]); B.u[4 + e] = bf16u(b1[e]);
        }
      } else {
        #pragma unroll
        for (int e = 0; e < 8; e++) { A.u[e] = 0; B.u[e] = 0; }
      }
      gacc = __builtin_amdgcn_mfma_f32_16x16x32_bf16(A.v, B.v, gacc, 0, 0, 0);
    }
    #pragma unroll
    for (int reg = 0; reg < 4; reg++)
      sm.g.G[mat][(mt * 16 + q * 4 + reg) * 16 + r] = gacc[reg];
    __syncthreads();
    for (int e = t; e < 1024; e += 256) {
      int j = e >> 4, i = e & 15;
      const float* Er = emb + j * 32;
      float eg2 = 0.f, eg3 = 0.f;
      #pragma unroll
      for (int cat = 0; cat < 32; cat++) {
        float ev = Er[cat];
        eg2 = fmaf(ev, sm.g.G[0][cat * 16 + i], eg2);
        eg3 = fmaf(ev, sm.g.G[1][cat * 16 + i], eg3);
      }
      sm.g.EG2[e] = eg2; sm.g.EG3[e] = eg3;
    }
    __syncthreads();
    #pragma unroll
    for (int l = 0; l < 3; l++) {
      for (int e = t; e < 512; e += 256) {
        int cat = e >> 4, i = e & 15;
        float acc = 0.f;
        for (int j = 0; j < 64; j++) {
          float a0 = alpha[j];
          float Al = a0;
          if (l >= 1) Al += alpha[64 + j];
          if (l >= 2) Al += alpha[128 + j];
          float u = Al * sm.g.EG2[j * 16 + i] - a0 * sm.g.EG3[j * 16 + i];
          acc = fmaf(emb[j * 32 + cat], u, acc);
        }
        VBase[(size_t)b * 1536 + l * 512 + e] = acc;
      }
    }
  }
}

// ---------------------------------------------------------------------------
// k_upd (layer l, grid 512 = 32 b x 16 tiles, 256 thr):
//  comb-lite: V = VBase_l − [l=1: ΣWpA; l=2: W1sum + ΣWpB] -> Vs (bf16)
//  B/B[nstar] prefetched EARLY (hidden under logits+softmax)
//  logits = S0 + sc*(V@X); softmax; [l==2: out, done]
//  else: Ep=E@Ps; B-update bf16; uacc = w@X^T;
//        Wchunk = E^T@(α_{l+1}∘uacc) -> WpOut;  [l==1: mt==0 writes W1sum]
// ---------------------------------------------------------------------------
__global__ __launch_bounds__(256) void k_upd(
    const float* __restrict__ x, const float* __restrict__ emb,
    const float* __restrict__ kpp, const float* __restrict__ alphaN,
    const float* __restrict__ VBase, const float* __restrict__ S0,
    const int* __restrict__ nstar,
    const float* __restrict__ WpIn, float* __restrict__ W1sum,
    const unsigned short* __restrict__ Bin, unsigned short* __restrict__ Bout,
    float* __restrict__ WpOut, int l, float* __restrict__ out)
{
  __shared__ unsigned short Xt[64 * 24];   // X^T [col][i]
  __shared__ unsigned short Xb[16 * 72];   // X [i][col]
  __shared__ unsigned short Eb[64 * 40];   // E [j][cat]
  __shared__ unsigned short Et[32 * 72];   // E^T [cat][j]
  __shared__ unsigned short Vs[32 * 24];   // V bf16 [cat][i]
  __shared__ unsigned short Ps[64 * 40];   // p bf16 [col][cat]
  __shared__ unsigned short Wsh[64 * 72];  // w bf16 [j][col]
  __shared__ float Ups[64 * 18];           // alpha-scaled Up chunk [j][i]
  int t = threadIdx.x;
  int b = blockIdx.x >> 4;
  int mt = blockIdx.x & 15;
  int n0 = mt * 64;
  int lane = t & 63, w = t >> 6;
  int r = lane & 15, q = lane >> 4;
  const float* xb = x + (size_t)b * DINR * NN;
  int mcol = n0 + w * 16 + r;

  // ---- early B prefetch (independent of softmax) ----
  int nst = 0;
  unsigned int pc[8], pg[8];
  if (l != 2) {
    nst = nstar[b * NN + mcol];
    const unsigned int* BC = reinterpret_cast<const unsigned int*>(
        Bin + ((size_t)b * NN + mcol) * 64);
    const unsigned int* BG = reinterpret_cast<const unsigned int*>(
        Bin + ((size_t)b * NN + nst) * 64);
    #pragma unroll
    for (int jt = 0; jt < 4; jt++) {
      pc[jt * 2]     = BC[jt * 8 + q * 2];
      pc[jt * 2 + 1] = BC[jt * 8 + q * 2 + 1];
      pg[jt * 2]     = BG[jt * 8 + q * 2];
      pg[jt * 2 + 1] = BG[jt * 8 + q * 2 + 1];
    }
  }

  // ---- staging (X, E, E^T) ----
  for (int e = t; e < 1024; e += 256) {
    int i = e >> 6, col = e & 63;
    unsigned short v = bf16u(xb[i * NN + n0 + col]);
    Xb[i * 72 + col] = v;
    Xt[col * 24 + i] = v;
  }
  for (int e = t; e < 2048; e += 256) {
    int j = e >> 5, cat = e & 31;
    unsigned short v = bf16u(emb[e]);
    Eb[j * 40 + cat] = v;
    Et[cat * 72 + j] = v;
  }
  // ---- comb-lite: V ----
  for (int e = t; e < 512; e += 256) {
    float acc = VBase[(size_t)b * 1536 + l * 512 + e];
    if (l == 1) {
      const float* pw = WpIn + (size_t)b * 16 * 512 + e;
      float s1 = 0.f;
      #pragma unroll 8
      for (int ch = 0; ch < 16; ch++) s1 += pw[ch * 512];
      if (mt == 0) W1sum[(size_t)b * 512 + e] = s1;
      acc -= s1;
    } else if (l == 2) {
      acc -= W1sum[(size_t)b * 512 + e];
      const float* pw = WpIn + (size_t)b * 16 * 512 + e;
      float s2 = 0.f;
      #pragma unroll 8
      for (int ch = 0; ch < 16; ch++) s2 += pw[ch * 512];
      acc -= s2;
    }
    Vs[(e >> 4) * 24 + (e & 15)] = bf16u(acc);
  }
  __syncthreads();

  float sc = kpp[0] * (1.0f / 1008.0f);
  s8 zero8 = {0, 0, 0, 0, 0, 0, 0, 0};

  // ---- logits = S0 + sc*(V@X) ----
  f4 sacc[2];
  {
    s8 bx = zero8;
    if (q < 2) bx = *reinterpret_cast<const s8*>(&Xt[(w * 16 + r) * 24 + q * 8]);
    #pragma unroll
    for (int ct = 0; ct < 2; ct++) {
      s8 av = zero8;
      if (q < 2) av = *reinterpret_cast<const s8*>(&Vs[(ct * 16 + r) * 24 + q * 8]);
      f4 z = {0.f, 0.f, 0.f, 0.f};
      f4 mm = __builtin_amdgcn_mfma_f32_16x16x32_bf16(av, bx, z, 0, 0, 0);
      #pragma unroll
      for (int reg = 0; reg < 4; reg++) {
        int cat = ct * 16 + q * 4 + reg;
        sacc[ct][reg] = S0[(size_t)b * 32 * NN + (size_t)cat * NN + mcol] + sc * mm[reg];
      }
    }
  }
  // ---- softmax ----
  float p[2][4];
  float mx = -3.4e38f;
  #pragma unroll
  for (int ct = 0; ct < 2; ct++)
    #pragma unroll
    for (int reg = 0; reg < 4; reg++) mx = fmaxf(mx, sacc[ct][reg]);
  mx = fmaxf(mx, __shfl_xor(mx, 16, 64));
  mx = fmaxf(mx, __shfl_xor(mx, 32, 64));
  float ss = 0.f;
  #pragma unroll
  for (int ct = 0; ct < 2; ct++)
    #pragma unroll
    for (int reg = 0; reg < 4; reg++) {
      p[ct][reg] = __expf(sacc[ct][reg] - mx);
      ss += p[ct][reg];
    }
  ss += __shfl_xor(ss, 16, 64);
  ss += __shfl_xor(ss, 32, 64);
  float inv = 1.0f / ss;
  #pragma unroll
  for (int ct = 0; ct < 2; ct++)
    #pragma unroll
    for (int reg = 0; reg < 4; reg++) p[ct][reg] *= inv;

  if (l == 2) {
    float* lo = out + ((size_t)b * NN + mcol) * 32;
    float* po = lo + (size_t)NB * NN * 32;
    #pragma unroll
    for (int ct = 0; ct < 2; ct++) {
      f4 vl = {sacc[ct][0], sacc[ct][1], sacc[ct][2], sacc[ct][3]};
      f4 vp = {p[ct][0], p[ct][1], p[ct][2], p[ct][3]};
      *reinterpret_cast<f4*>(lo + ct * 16 + q * 4) = vl;
      *reinterpret_cast<f4*>(po + ct * 16 + q * 4) = vp;
    }
    return;
  }

  // ---- p -> Ps (wave-local) ----
  #pragma unroll
  for (int ct = 0; ct < 2; ct++) {
    unsigned int u0 = (unsigned int)bf16u(p[ct][0]) | ((unsigned int)bf16u(p[ct][1]) << 16);
    unsigned int u1 = (unsigned int)bf16u(p[ct][2]) | ((unsigned int)bf16u(p[ct][3]) << 16);
    unsigned int base = (w * 16 + r) * 40 + ct * 16 + q * 4;
    *reinterpret_cast<unsigned int*>(&Ps[base]) = u0;
    *reinterpret_cast<unsigned int*>(&Ps[base + 2]) = u1;
  }
  // ---- GEMM3: Ep = Eb @ Ps ----
  f4 eacc[4];
  {
    s8 bp = *reinterpret_cast<const s8*>(&Ps[(w * 16 + r) * 40 + q * 8]);
    #pragma unroll
    for (int jt = 0; jt < 4; jt++) {
      s8 ae = *reinterpret_cast<const s8*>(&Eb[(jt * 16 + r) * 40 + q * 8]);
      f4 z = {0.f, 0.f, 0.f, 0.f};
      eacc[jt] = __builtin_amdgcn_mfma_f32_16x16x32_bf16(ae, bp, z, 0, 0, 0);
    }
  }
  // ---- B update (bf16, col-major [n][64]), inputs prefetched ----
  float vv[4][4];
  {
    unsigned int* BO = reinterpret_cast<unsigned int*>(
        Bout + ((size_t)b * NN + mcol) * 64);
    const float invM = 1.0f / 1008.0f;
    #pragma unroll
    for (int jt = 0; jt < 4; jt++) {
      unsigned int c0 = pc[jt * 2], c1 = pc[jt * 2 + 1];
      unsigned int g0 = pg[jt * 2], g1 = pg[jt * 2 + 1];
      float bc[4] = { bfu2f(c0 & 0xFFFFu), bfu2f(c0 >> 16),
                      bfu2f(c1 & 0xFFFFu), bfu2f(c1 >> 16) };
      float bg[4] = { bfu2f(g0 & 0xFFFFu), bfu2f(g0 >> 16),
                      bfu2f(g1 & 0xFFFFu), bfu2f(g1 >> 16) };
      float vo[4];
      #pragma unroll
      for (int reg = 0; reg < 4; reg++) {
        vo[reg] = bc[reg] - bg[reg] * invM + eacc[jt][reg];
        vv[jt][reg] = vo[reg];
      }
      BO[jt * 8 + q * 2]     = (unsigned int)bf16u(vo[0]) | ((unsigned int)bf16u(vo[1]) << 16);
      BO[jt * 8 + q * 2 + 1] = (unsigned int)bf16u(vo[2]) | ((unsigned int)bf16u(vo[3]) << 16);
    }
  }
  // ---- w -> Wsh (masked) ----
  {
    bool live = (mcol < 1008);
    #pragma unroll
    for (int jt = 0; jt < 4; jt++)
      #pragma unroll
      for (int reg = 0; reg < 4; reg++)
        Wsh[(jt * 16 + q * 4 + reg) * 72 + (w * 16 + r)] =
            live ? bf16u(vv[jt][reg]) : (unsigned short)0;
  }
  __syncthreads();
  // ---- GEMM4: uacc = w @ X^T (wave w -> j-tile w) ----
  f4 uacc = {0.f, 0.f, 0.f, 0.f};
  #pragma unroll
  for (int kt = 0; kt < 2; kt++) {
    s8 aw = *reinterpret_cast<const s8*>(&Wsh[(w * 16 + r) * 72 + kt * 32 + q * 8]);
    s8 bxx = *reinterpret_cast<const s8*>(&Xb[r * 72 + kt * 32 + q * 8]);
    uacc = __builtin_amdgcn_mfma_f32_16x16x32_bf16(aw, bxx, uacc, 0, 0, 0);
  }
  // ---- stage alpha-scaled Up chunk ----
  #pragma unroll
  for (int reg = 0; reg < 4; reg++)
    Ups[(w * 16 + q * 4 + reg) * 18 + r] = alphaN[w * 16 + q * 4 + reg] * uacc[reg];
  __syncthreads();
  // ---- Wchunk = E^T @ (alphaN∘Up) (waves 0-1, cat tile = w) ----
  if (w < 2) {
    f4 wacc = {0.f, 0.f, 0.f, 0.f};
    #pragma unroll
    for (int kt = 0; kt < 2; kt++) {
      s8 ae = *reinterpret_cast<const s8*>(&Et[(w * 16 + r) * 72 + kt * 32 + q * 8]);
      union { s8 v; unsigned short u[8]; } Bu;
      #pragma unroll
      for (int e = 0; e < 8; e++)
        Bu.u[e] = bf16u(Ups[(kt * 32 + q * 8 + e) * 18 + r]);
      wacc = __builtin_amdgcn_mfma_f32_16x16x32_bf16(ae, Bu.v, wacc, 0, 0, 0);
    }
    float* wp = WpOut + ((size_t)(b * 16 + mt)) * 512;
    #pragma unroll
    for (int reg = 0; reg < 4; reg++)
      wp[(w * 16 + q * 4 + reg) * 16 + r] = wacc[reg];
  }
}

extern "C" void kernel_launch(void* const* d_in, const int* in_sizes, int n_in,
                              void* d_out, int out_size, void* d_ws, size_t ws_size,
                              hipStream_t stream)
{
  const float* x     = (const float*)d_in[0];
  const float* alpha = (const float*)d_in[1];
  const float* kp    = (const float*)d_in[2];
  const float* emb   = (const float*)d_in[3];
  float* ws = (float*)d_ws;
  unsigned short* B0u = (unsigned short*)(ws + OFF_B0);
  unsigned short* B1u = (unsigned short*)(ws + OFF_B1);
  float* S0   = ws + OFF_S0;
  float* VB   = ws + OFF_VB;
  float* WpA  = ws + OFF_WPA;
  float* WpB  = ws + OFF_WPB;
  float* W1s  = ws + OFF_W1S;
  int*   ns   = (int*)(ws + OFF_NS);
  float* out  = (float*)d_out;

  k_init<<<1568, 256, 0, stream>>>(x, emb, alpha, B0u, S0, VB, ns);
  // layer 0: B0->B1, writes WpA (alpha1-scaled W chunks)
  k_upd<<<512, 256, 0, stream>>>(x, emb, kp, alpha + 64, VB, S0, ns,
                                 WpA, W1s, B0u, B1u, WpA, 0, out);
  // layer 1: B1->B0, reads WpA (W1), writes W1sum + WpB (alpha2-scaled)
  k_upd<<<512, 256, 0, stream>>>(x, emb, kp, alpha + 128, VB, S0, ns,
                                 WpA, W1s, B1u, B0u, WpB, 1, out);
  // layer 2 (last): reads W1sum + WpB, writes out
  k_upd<<<512, 256, 0, stream>>>(x, emb, kp, alpha, VB, S0, ns,
                                 WpB, W1s, B0u, B1u, WpA, 2, out);
}

// Round 21
// 63.991 us; speedup vs baseline: 1.6702x; 1.0941x over previous
//
#include <hip/hip_runtime.h>
#include <hip/hip_bf16.h>

#define NB 32
#define NN 1024
#define DINR 144

typedef __attribute__((ext_vector_type(4))) float f4;
typedef __attribute__((ext_vector_type(8))) short s8;

// ws float offsets
#define OFF_B0   (0u)                          // bf16 [32][1024][64]
#define OFF_B1   (1048576u)
#define OFF_S0   (2097152u)                    // f32 [32][32][1024]
#define OFF_VB   (3145728u)                    // f32 [32][3][512]
#define OFF_WPA  (3194880u)                    // f32 [32][16][512]
#define OFF_WPB  (3457024u)
#define OFF_W1S  (3719168u)                    // f32 [32][512]
#define OFF_NS   (3735552u)

static __device__ __forceinline__ unsigned short bf16u(float f) {
  __hip_bfloat16 h = __float2bfloat16(f);
  return *reinterpret_cast<unsigned short*>(&h);
}
static __device__ __forceinline__ float bfu2f(unsigned int u16) {
  unsigned int v = u16 << 16;
  return __uint_as_float(v);
}

// ---------------------------------------------------------------------------
// k_init (grid 1568), block roles REORDERED so the 32 Gram blocks launch first:
//  blocks [0,32): per-batch Gram via MFMA (K=1008 from global) + VBase_l
//  blocks [32,1056): dense: stage x rows 48..144 (stride 33, odd -> <=2-way
//    banks) + E; B0 = E@x3 (bf16 col-major, MFMA); S0 = E^T@x[80:144] (f32)
//  blocks [1056,1568): nstar argmax; XT chunk-XOR-swizzled (conflict-free)
// ---------------------------------------------------------------------------
__global__ __launch_bounds__(256) void k_init(
    const float* __restrict__ x, const float* __restrict__ emb,
    const float* __restrict__ alpha,
    unsigned short* __restrict__ Bt, float* __restrict__ S0,
    float* __restrict__ VBase, int* __restrict__ nstar)
{
  __shared__ union {
    unsigned int XT[NN * 8];                   // 32768 B (argmax, swizzled)
    struct {
      float xs[96 * 33];                       // 12672 B (rows 48..144)
      unsigned int Eb[64 * 16];                // 4096 B
      unsigned short etr[32 * 72];             // 4608 B
    } d;
    struct {
      float G[2][512];
      float EG2[1024];
      float EG3[1024];
    } g;
  } sm;
  int t = threadIdx.x;
  if (blockIdx.x < 32) {
    // ---- Gram + VBase, one block per batch (runs first, hides under rest) --
    int b = blockIdx.x;
    const float* xb = x + (size_t)b * DINR * NN;
    int lane = t & 63, w = t >> 6;
    int r = lane & 15, q = lane >> 4;
    int mat = w >> 1, mt = w & 1;
    const float* arow = xb + (size_t)(16 + mat * 32 + mt * 16 + r) * NN;
    const float* brow = xb + (size_t)r * NN;
    f4 gacc = {0.f, 0.f, 0.f, 0.f};
    for (int kt = 0; kt < 32; kt++) {
      int k0 = kt * 32 + q * 8;
      union { s8 v; unsigned short u[8]; } A, B;
      if (kt < 31 || q < 2) {
        f4 a0 = *reinterpret_cast<const f4*>(arow + k0);
        f4 a1 = *reinterpret_cast<const f4*>(arow + k0 + 4);
        f4 b0 = *reinterpret_cast<const f4*>(brow + k0);
        f4 b1 = *reinterpret_cast<const f4*>(brow + k0 + 4);
        #pragma unroll
        for (int e = 0; e < 4; e++) {
          A.u[e] = bf16u(a0[e]); A.u[4 + e] = bf16u(a1[e]);
          B.u[e] = bf16u(b0[e]); B.u[4 + e] = bf16u(b1[e]);
        }
      } else {
        #pragma unroll
        for (int e = 0; e < 8; e++) { A.u[e] = 0; B.u[e] = 0; }
      }
      gacc = __builtin_amdgcn_mfma_f32_16x16x32_bf16(A.v, B.v, gacc, 0, 0, 0);
    }
    #pragma unroll
    for (int reg = 0; reg < 4; reg++)
      sm.g.G[mat][(mt * 16 + q * 4 + reg) * 16 + r] = gacc[reg];
    __syncthreads();
    for (int e = t; e < 1024; e += 256) {
      int j = e >> 4, i = e & 15;
      const float* Er = emb + j * 32;
      float eg2 = 0.f, eg3 = 0.f;
      #pragma unroll
      for (int cat = 0; cat < 32; cat++) {
        float ev = Er[cat];
        eg2 = fmaf(ev, sm.g.G[0][cat * 16 + i], eg2);
        eg3 = fmaf(ev, sm.g.G[1][cat * 16 + i], eg3);
      }
      sm.g.EG2[e] = eg2; sm.g.EG3[e] = eg3;
    }
    __syncthreads();
    #pragma unroll
    for (int l = 0; l < 3; l++) {
      for (int e = t; e < 512; e += 256) {
        int cat = e >> 4, i = e & 15;
        float acc = 0.f;
        for (int j = 0; j < 64; j++) {
          float a0 = alpha[j];
          float Al = a0;
          if (l >= 1) Al += alpha[64 + j];
          if (l >= 2) Al += alpha[128 + j];
          float u = Al * sm.g.EG2[j * 16 + i] - a0 * sm.g.EG3[j * 16 + i];
          acc = fmaf(emb[j * 32 + cat], u, acc);
        }
        VBase[(size_t)b * 1536 + l * 512 + e] = acc;
      }
    }
  } else if (blockIdx.x < 1056) {
    int a = blockIdx.x - 32;
    int b = a >> 5;
    int ct = a & 31;
    int n0 = ct * 32;
    const float* xb = x + (size_t)b * DINR * NN;
    for (int idx = t; idx < 96 * 32; idx += 256) {
      int row = idx >> 5, col = idx & 31;
      sm.d.xs[row * 33 + col] = xb[(48 + row) * NN + n0 + col];
    }
    for (int e = t; e < 1024; e += 256) {
      int j = e >> 4, hp = e & 15;
      float f0 = emb[j * 32 + hp * 2];
      float f1 = emb[j * 32 + hp * 2 + 1];
      sm.d.Eb[j * 16 + hp] =
          (unsigned int)bf16u(f0) | ((unsigned int)bf16u(f1) << 16);
    }
    for (int e = t; e < 2048; e += 256) {
      int j = e >> 5, cat = e & 31;
      sm.d.etr[cat * 72 + j] = bf16u(emb[e]);
    }
    __syncthreads();
    int lane = t & 63, w = t >> 6;
    int r = lane & 15, q = lane >> 4;
    // B0 = E @ x3 (x3 = local rows 0..32)
    {
      s8 af = *reinterpret_cast<const s8*>(&sm.d.Eb[(w * 16 + r) * 16 + q * 4]);
      #pragma unroll
      for (int nt = 0; nt < 2; nt++) {
        union { s8 v; unsigned short u[8]; } B;
        #pragma unroll
        for (int e = 0; e < 8; e++)
          B.u[e] = bf16u(sm.d.xs[(q * 8 + e) * 33 + nt * 16 + r]);
        f4 acc = {0.f, 0.f, 0.f, 0.f};
        acc = __builtin_amdgcn_mfma_f32_16x16x32_bf16(af, B.v, acc, 0, 0, 0);
        int n = n0 + nt * 16 + r;
        unsigned int p0 = (unsigned int)bf16u(acc[0]) | ((unsigned int)bf16u(acc[1]) << 16);
        unsigned int p1 = (unsigned int)bf16u(acc[2]) | ((unsigned int)bf16u(acc[3]) << 16);
        unsigned int* dst = reinterpret_cast<unsigned int*>(
            Bt + ((size_t)b * NN + n) * 64 + w * 16 + q * 4);
        dst[0] = p0; dst[1] = p1;
      }
    }
    // S0 = E^T @ C0 (C0 = local rows 32..96)
    {
      int mt = w & 1;
      int nt = w >> 1;
      f4 acc = {0.f, 0.f, 0.f, 0.f};
      #pragma unroll
      for (int kt = 0; kt < 2; kt++) {
        s8 ae = *reinterpret_cast<const s8*>(&sm.d.etr[(mt * 16 + r) * 72 + kt * 32 + q * 8]);
        union { s8 v; unsigned short u[8]; } Bx;
        #pragma unroll
        for (int e = 0; e < 8; e++)
          Bx.u[e] = bf16u(sm.d.xs[(32 + kt * 32 + q * 8 + e) * 33 + nt * 16 + r]);
        acc = __builtin_amdgcn_mfma_f32_16x16x32_bf16(ae, Bx.v, acc, 0, 0, 0);
      }
      #pragma unroll
      for (int reg = 0; reg < 4; reg++)
        S0[(size_t)b * 32 * NN + (size_t)(mt * 16 + q * 4 + reg) * NN + n0 + nt * 16 + r] = acc[reg];
    }
  } else {
    int a = blockIdx.x - 1056;
    int b = a >> 4;
    int mg = a & 15;
    const float* xb = x + (size_t)b * DINR * NN;
    // stage X^T bf16-pair packed, chunk-XOR-swizzled:
    //   logical chunk c (=h>>2) of row n stored at physical chunk c^((n>>2)&3)
    #pragma unroll
    for (int rep = 0; rep < 4; rep++) {
      int n = t + (rep << 8);
      unsigned int pk[8];
      #pragma unroll
      for (int h = 0; h < 8; h++) {
        unsigned int u0 = __float_as_uint(xb[(2*h) * NN + n]);
        unsigned int u1 = __float_as_uint(xb[(2*h+1) * NN + n]);
        pk[h] = (u0 >> 16) | (u1 & 0xFFFF0000u);
      }
      int sw = (n >> 2) & 3;
      #pragma unroll
      for (int h = 0; h < 8; h++)
        sm.XT[n * 8 + (((h >> 2) ^ sw) << 2) + (h & 3)] = pk[h];
    }
    __syncthreads();
    int w = t >> 6;
    int lane = t & 63;
    int r = lane & 15;
    int g = lane >> 4;
    int mt = mg * 64 + w * 16;
    int sw = (r >> 2) & 3;      // rows mt+r and nt*16+r: (row>>2)&3 == (r>>2)&3
    s8 zero8 = {0,0,0,0,0,0,0,0};
    s8 afrag = zero8;
    if (g < 2) afrag = *reinterpret_cast<const s8*>(&sm.XT[(mt + r) * 8 + ((g ^ sw) << 2)]);
    float bestv[4];
    int besti[4];
    #pragma unroll
    for (int j = 0; j < 4; j++) { bestv[j] = -3.4e38f; besti[j] = 0x7FFFFFFF; }
    for (int nt = 0; nt < 63; nt++) {
      s8 bfrag = zero8;
      if (g < 2) bfrag = *reinterpret_cast<const s8*>(&sm.XT[(nt*16 + r) * 8 + ((g ^ sw) << 2)]);
      f4 acc = {0.f, 0.f, 0.f, 0.f};
      acc = __builtin_amdgcn_mfma_f32_16x16x32_bf16(afrag, bfrag, acc, 0, 0, 0);
      int n = nt * 16 + r;
      #pragma unroll
      for (int j = 0; j < 4; j++) {
        float v = acc[j];
        bool better = (v > bestv[j]) || (v == bestv[j] && n < besti[j]);
        if (better) { bestv[j] = v; besti[j] = n; }
      }
    }
    #pragma unroll
    for (int s = 1; s < 16; s <<= 1) {
      #pragma unroll
      for (int j = 0; j < 4; j++) {
        float ov = __shfl_xor(bestv[j], s, 64);
        int   oi = __shfl_xor(besti[j], s, 64);
        bool better = (ov > bestv[j]) || (ov == bestv[j] && oi < besti[j]);
        if (better) { bestv[j] = ov; besti[j] = oi; }
      }
    }
    if (r == 0) {
      #pragma unroll
      for (int j = 0; j < 4; j++)
        nstar[b * NN + mt + g * 4 + j] = besti[j];
    }
  }
}

// ---------------------------------------------------------------------------
// k_upd (unchanged from R20 — proven)
// ---------------------------------------------------------------------------
__global__ __launch_bounds__(256) void k_upd(
    const float* __restrict__ x, const float* __restrict__ emb,
    const float* __restrict__ kpp, const float* __restrict__ alphaN,
    const float* __restrict__ VBase, const float* __restrict__ S0,
    const int* __restrict__ nstar,
    const float* __restrict__ WpIn, float* __restrict__ W1sum,
    const unsigned short* __restrict__ Bin, unsigned short* __restrict__ Bout,
    float* __restrict__ WpOut, int l, float* __restrict__ out)
{
  __shared__ unsigned short Xt[64 * 24];   // X^T [col][i]
  __shared__ unsigned short Xb[16 * 72];   // X [i][col]
  __shared__ unsigned short Eb[64 * 40];   // E [j][cat]
  __shared__ unsigned short Et[32 * 72];   // E^T [cat][j]
  __shared__ unsigned short Vs[32 * 24];   // V bf16 [cat][i]
  __shared__ unsigned short Ps[64 * 40];   // p bf16 [col][cat]
  __shared__ unsigned short Wsh[64 * 72];  // w bf16 [j][col]
  __shared__ float Ups[64 * 18];           // alpha-scaled Up chunk [j][i]
  int t = threadIdx.x;
  int b = blockIdx.x >> 4;
  int mt = blockIdx.x & 15;
  int n0 = mt * 64;
  int lane = t & 63, w = t >> 6;
  int r = lane & 15, q = lane >> 4;
  const float* xb = x + (size_t)b * DINR * NN;
  int mcol = n0 + w * 16 + r;

  // ---- early B prefetch (independent of softmax) ----
  int nst = 0;
  unsigned int pc[8], pg[8];
  if (l != 2) {
    nst = nstar[b * NN + mcol];
    const unsigned int* BC = reinterpret_cast<const unsigned int*>(
        Bin + ((size_t)b * NN + mcol) * 64);
    const unsigned int* BG = reinterpret_cast<const unsigned int*>(
        Bin + ((size_t)b * NN + nst) * 64);
    #pragma unroll
    for (int jt = 0; jt < 4; jt++) {
      pc[jt * 2]     = BC[jt * 8 + q * 2];
      pc[jt * 2 + 1] = BC[jt * 8 + q * 2 + 1];
      pg[jt * 2]     = BG[jt * 8 + q * 2];
      pg[jt * 2 + 1] = BG[jt * 8 + q * 2 + 1];
    }
  }

  // ---- staging (X, E, E^T) ----
  for (int e = t; e < 1024; e += 256) {
    int i = e >> 6, col = e & 63;
    unsigned short v = bf16u(xb[i * NN + n0 + col]);
    Xb[i * 72 + col] = v;
    Xt[col * 24 + i] = v;
  }
  for (int e = t; e < 2048; e += 256) {
    int j = e >> 5, cat = e & 31;
    unsigned short v = bf16u(emb[e]);
    Eb[j * 40 + cat] = v;
    Et[cat * 72 + j] = v;
  }
  // ---- comb-lite: V ----
  for (int e = t; e < 512; e += 256) {
    float acc = VBase[(size_t)b * 1536 + l * 512 + e];
    if (l == 1) {
      const float* pw = WpIn + (size_t)b * 16 * 512 + e;
      float s1 = 0.f;
      #pragma unroll 8
      for (int ch = 0; ch < 16; ch++) s1 += pw[ch * 512];
      if (mt == 0) W1sum[(size_t)b * 512 + e] = s1;
      acc -= s1;
    } else if (l == 2) {
      acc -= W1sum[(size_t)b * 512 + e];
      const float* pw = WpIn + (size_t)b * 16 * 512 + e;
      float s2 = 0.f;
      #pragma unroll 8
      for (int ch = 0; ch < 16; ch++) s2 += pw[ch * 512];
      acc -= s2;
    }
    Vs[(e >> 4) * 24 + (e & 15)] = bf16u(acc);
  }
  __syncthreads();

  float sc = kpp[0] * (1.0f / 1008.0f);
  s8 zero8 = {0, 0, 0, 0, 0, 0, 0, 0};

  // ---- logits = S0 + sc*(V@X) ----
  f4 sacc[2];
  {
    s8 bx = zero8;
    if (q < 2) bx = *reinterpret_cast<const s8*>(&Xt[(w * 16 + r) * 24 + q * 8]);
    #pragma unroll
    for (int ct = 0; ct < 2; ct++) {
      s8 av = zero8;
      if (q < 2) av = *reinterpret_cast<const s8*>(&Vs[(ct * 16 + r) * 24 + q * 8]);
      f4 z = {0.f, 0.f, 0.f, 0.f};
      f4 mm = __builtin_amdgcn_mfma_f32_16x16x32_bf16(av, bx, z, 0, 0, 0);
      #pragma unroll
      for (int reg = 0; reg < 4; reg++) {
        int cat = ct * 16 + q * 4 + reg;
        sacc[ct][reg] = S0[(size_t)b * 32 * NN + (size_t)cat * NN + mcol] + sc * mm[reg];
      }
    }
  }
  // ---- softmax ----
  float p[2][4];
  float mx = -3.4e38f;
  #pragma unroll
  for (int ct = 0; ct < 2; ct++)
    #pragma unroll
    for (int reg = 0; reg < 4; reg++) mx = fmaxf(mx, sacc[ct][reg]);
  mx = fmaxf(mx, __shfl_xor(mx, 16, 64));
  mx = fmaxf(mx, __shfl_xor(mx, 32, 64));
  float ss = 0.f;
  #pragma unroll
  for (int ct = 0; ct < 2; ct++)
    #pragma unroll
    for (int reg = 0; reg < 4; reg++) {
      p[ct][reg] = __expf(sacc[ct][reg] - mx);
      ss += p[ct][reg];
    }
  ss += __shfl_xor(ss, 16, 64);
  ss += __shfl_xor(ss, 32, 64);
  float inv = 1.0f / ss;
  #pragma unroll
  for (int ct = 0; ct < 2; ct++)
    #pragma unroll
    for (int reg = 0; reg < 4; reg++) p[ct][reg] *= inv;

  if (l == 2) {
    float* lo = out + ((size_t)b * NN + mcol) * 32;
    float* po = lo + (size_t)NB * NN * 32;
    #pragma unroll
    for (int ct = 0; ct < 2; ct++) {
      f4 vl = {sacc[ct][0], sacc[ct][1], sacc[ct][2], sacc[ct][3]};
      f4 vp = {p[ct][0], p[ct][1], p[ct][2], p[ct][3]};
      *reinterpret_cast<f4*>(lo + ct * 16 + q * 4) = vl;
      *reinterpret_cast<f4*>(po + ct * 16 + q * 4) = vp;
    }
    return;
  }

  // ---- p -> Ps (wave-local) ----
  #pragma unroll
  for (int ct = 0; ct < 2; ct++) {
    unsigned int u0 = (unsigned int)bf16u(p[ct][0]) | ((unsigned int)bf16u(p[ct][1]) << 16);
    unsigned int u1 = (unsigned int)bf16u(p[ct][2]) | ((unsigned int)bf16u(p[ct][3]) << 16);
    unsigned int base = (w * 16 + r) * 40 + ct * 16 + q * 4;
    *reinterpret_cast<unsigned int*>(&Ps[base]) = u0;
    *reinterpret_cast<unsigned int*>(&Ps[base + 2]) = u1;
  }
  // ---- GEMM3: Ep = Eb @ Ps ----
  f4 eacc[4];
  {
    s8 bp = *reinterpret_cast<const s8*>(&Ps[(w * 16 + r) * 40 + q * 8]);
    #pragma unroll
    for (int jt = 0; jt < 4; jt++) {
      s8 ae = *reinterpret_cast<const s8*>(&Eb[(jt * 16 + r) * 40 + q * 8]);
      f4 z = {0.f, 0.f, 0.f, 0.f};
      eacc[jt] = __builtin_amdgcn_mfma_f32_16x16x32_bf16(ae, bp, z, 0, 0, 0);
    }
  }
  // ---- B update (bf16, col-major [n][64]), inputs prefetched ----
  float vv[4][4];
  {
    unsigned int* BO = reinterpret_cast<unsigned int*>(
        Bout + ((size_t)b * NN + mcol) * 64);
    const float invM = 1.0f / 1008.0f;
    #pragma unroll
    for (int jt = 0; jt < 4; jt++) {
      unsigned int c0 = pc[jt * 2], c1 = pc[jt * 2 + 1];
      unsigned int g0 = pg[jt * 2], g1 = pg[jt * 2 + 1];
      float bc[4] = { bfu2f(c0 & 0xFFFFu), bfu2f(c0 >> 16),
                      bfu2f(c1 & 0xFFFFu), bfu2f(c1 >> 16) };
      float bg[4] = { bfu2f(g0 & 0xFFFFu), bfu2f(g0 >> 16),
                      bfu2f(g1 & 0xFFFFu), bfu2f(g1 >> 16) };
      float vo[4];
      #pragma unroll
      for (int reg = 0; reg < 4; reg++) {
        vo[reg] = bc[reg] - bg[reg] * invM + eacc[jt][reg];
        vv[jt][reg] = vo[reg];
      }
      BO[jt * 8 + q * 2]     = (unsigned int)bf16u(vo[0]) | ((unsigned int)bf16u(vo[1]) << 16);
      BO[jt * 8 + q * 2 + 1] = (unsigned int)bf16u(vo[2]) | ((unsigned int)bf16u(vo[3]) << 16);
    }
  }
  // ---- w -> Wsh (masked) ----
  {
    bool live = (mcol < 1008);
    #pragma unroll
    for (int jt = 0; jt < 4; jt++)
      #pragma unroll
      for (int reg = 0; reg < 4; reg++)
        Wsh[(jt * 16 + q * 4 + reg) * 72 + (w * 16 + r)] =
            live ? bf16u(vv[jt][reg]) : (unsigned short)0;
  }
  __syncthreads();
  // ---- GEMM4: uacc = w @ X^T (wave w -> j-tile w) ----
  f4 uacc = {0.f, 0.f, 0.f, 0.f};
  #pragma unroll
  for (int kt = 0; kt < 2; kt++) {
    s8 aw = *reinterpret_cast<const s8*>(&Wsh[(w * 16 + r) * 72 + kt * 32 + q * 8]);
    s8 bxx = *reinterpret_cast<const s8*>(&Xb[r * 72 + kt * 32 + q * 8]);
    uacc = __builtin_amdgcn_mfma_f32_16x16x32_bf16(aw, bxx, uacc, 0, 0, 0);
  }
  // ---- stage alpha-scaled Up chunk ----
  #pragma unroll
  for (int reg = 0; reg < 4; reg++)
    Ups[(w * 16 + q * 4 + reg) * 18 + r] = alphaN[w * 16 + q * 4 + reg] * uacc[reg];
  __syncthreads();
  // ---- Wchunk = E^T @ (alphaN∘Up) (waves 0-1, cat tile = w) ----
  if (w < 2) {
    f4 wacc = {0.f, 0.f, 0.f, 0.f};
    #pragma unroll
    for (int kt = 0; kt < 2; kt++) {
      s8 ae = *reinterpret_cast<const s8*>(&Et[(w * 16 + r) * 72 + kt * 32 + q * 8]);
      union { s8 v; unsigned short u[8]; } Bu;
      #pragma unroll
      for (int e = 0; e < 8; e++)
        Bu.u[e] = bf16u(Ups[(kt * 32 + q * 8 + e) * 18 + r]);
      wacc = __builtin_amdgcn_mfma_f32_16x16x32_bf16(ae, Bu.v, wacc, 0, 0, 0);
    }
    float* wp = WpOut + ((size_t)(b * 16 + mt)) * 512;
    #pragma unroll
    for (int reg = 0; reg < 4; reg++)
      wp[(w * 16 + q * 4 + reg) * 16 + r] = wacc[reg];
  }
}

extern "C" void kernel_launch(void* const* d_in, const int* in_sizes, int n_in,
                              void* d_out, int out_size, void* d_ws, size_t ws_size,
                              hipStream_t stream)
{
  const float* x     = (const float*)d_in[0];
  const float* alpha = (const float*)d_in[1];
  const float* kp    = (const float*)d_in[2];
  const float* emb   = (const float*)d_in[3];
  float* ws = (float*)d_ws;
  unsigned short* B0u = (unsigned short*)(ws + OFF_B0);
  unsigned short* B1u = (unsigned short*)(ws + OFF_B1);
  float* S0   = ws + OFF_S0;
  float* VB   = ws + OFF_VB;
  float* WpA  = ws + OFF_WPA;
  float* WpB  = ws + OFF_WPB;
  float* W1s  = ws + OFF_W1S;
  int*   ns   = (int*)(ws + OFF_NS);
  float* out  = (float*)d_out;

  k_init<<<1568, 256, 0, stream>>>(x, emb, alpha, B0u, S0, VB, ns);
  // layer 0: B0->B1, writes WpA (alpha1-scaled W chunks)
  k_upd<<<512, 256, 0, stream>>>(x, emb, kp, alpha + 64, VB, S0, ns,
                                 WpA, W1s, B0u, B1u, WpA, 0, out);
  // layer 1: B1->B0, reads WpA (W1), writes W1sum + WpB (alpha2-scaled)
  k_upd<<<512, 256, 0, stream>>>(x, emb, kp, alpha + 128, VB, S0, ns,
                                 WpA, W1s, B1u, B0u, WpB, 1, out);
  // layer 2 (last): reads W1sum + WpB, writes out
  k_upd<<<512, 256, 0, stream>>>(x, emb, kp, alpha, VB, S0, ns,
                                 WpB, W1s, B0u, B1u, WpA, 2, out);
}

// Round 22
// 59.420 us; speedup vs baseline: 1.7986x; 1.0769x over previous
//
#include <hip/hip_runtime.h>
#include <hip/hip_bf16.h>

#define NB 32
#define NN 1024
#define DINR 144

typedef __attribute__((ext_vector_type(4))) float f4;
typedef __attribute__((ext_vector_type(8))) short s8;
typedef __attribute__((ext_vector_type(4))) unsigned int u4;

// ws float offsets
#define OFF_B0   (0u)                          // bf16 [32][1024][64]
#define OFF_B1   (1048576u)
#define OFF_S0   (2097152u)                    // f32 [32][32][1024]
#define OFF_VB   (3145728u)                    // f32 [32][3][512]
#define OFF_WPA  (3194880u)                    // f32 [32][16][512]
#define OFF_WPB  (3457024u)
#define OFF_W1S  (3719168u)                    // f32 [32][512]
#define OFF_NS   (3735552u)

static __device__ __forceinline__ unsigned short bf16u(float f) {
  __hip_bfloat16 h = __float2bfloat16(f);
  return *reinterpret_cast<unsigned short*>(&h);
}
static __device__ __forceinline__ float bfu2f(unsigned int u16) {
  unsigned int v = u16 << 16;
  return __uint_as_float(v);
}

// ---------------------------------------------------------------------------
// k_init (grid 1568):
//  blocks [0,32): per-batch Gram (MFMA, dual-acc K-loop) + EG + VBase,
//    all inner loops on LDS-staged embT/alphaC (no scalar-global loops)
//  blocks [32,1056): dense: B0 = E@x3 (bf16 col-major); S0 = E^T@x[80:144]
//  blocks [1056,1568): nstar argmax; X^T in chunk-split layout XTc[2][n][4]
// ---------------------------------------------------------------------------
__global__ __launch_bounds__(256) void k_init(
    const float* __restrict__ x, const float* __restrict__ emb,
    const float* __restrict__ alpha,
    unsigned short* __restrict__ Bt, float* __restrict__ S0,
    float* __restrict__ VBase, int* __restrict__ nstar)
{
  __shared__ union {
    unsigned int XTc[2][4096];                 // 32768 B (argmax, chunk-split)
    struct {
      float xs[96 * 33];                       // 12672 B (rows 48..144)
      unsigned int Eb[64 * 16];                // 4096 B
      unsigned short etr[32 * 72];             // 4608 B
    } d;
    struct {
      float G[2][512];                         // 4096 B
      float EG2[1024];                         // 4096 B
      float EG3[1024];                         // 4096 B
      float embT[32 * 65];                     // 8320 B  [cat][j]
      float alphaC[3 * 64];                    // 768 B   cumulative alpha
    } g;
  } sm;
  int t = threadIdx.x;
  if (blockIdx.x < 32) {
    // ---- Gram + VBase, one block per batch ----
    int b = blockIdx.x;
    const float* xb = x + (size_t)b * DINR * NN;
    // stage embT (transposed, stride 65) + cumulative alpha
    for (int e = t; e < 2048; e += 256) {
      int j = e >> 5, cat = e & 31;
      sm.g.embT[cat * 65 + j] = emb[e];
    }
    if (t < 64) {
      float a0 = alpha[t];
      float a1 = a0 + alpha[64 + t];
      float a2 = a1 + alpha[128 + t];
      sm.g.alphaC[t] = a0;
      sm.g.alphaC[64 + t] = a1;
      sm.g.alphaC[128 + t] = a2;
    }
    int lane = t & 63, w = t >> 6;
    int r = lane & 15, q = lane >> 4;
    int mat = w >> 1, mt = w & 1;
    const float* arow = xb + (size_t)(16 + mat * 32 + mt * 16 + r) * NN;
    const float* brow = xb + (size_t)r * NN;
    f4 g0 = {0.f, 0.f, 0.f, 0.f};
    f4 g1 = {0.f, 0.f, 0.f, 0.f};
    for (int kt = 0; kt < 32; kt += 2) {
      // even iteration (never masked: kt <= 30)
      {
        int k0 = kt * 32 + q * 8;
        union { s8 v; unsigned short u[8]; } A, B;
        f4 a0v = *reinterpret_cast<const f4*>(arow + k0);
        f4 a1v = *reinterpret_cast<const f4*>(arow + k0 + 4);
        f4 b0v = *reinterpret_cast<const f4*>(brow + k0);
        f4 b1v = *reinterpret_cast<const f4*>(brow + k0 + 4);
        #pragma unroll
        for (int e = 0; e < 4; e++) {
          A.u[e] = bf16u(a0v[e]); A.u[4 + e] = bf16u(a1v[e]);
          B.u[e] = bf16u(b0v[e]); B.u[4 + e] = bf16u(b1v[e]);
        }
        g0 = __builtin_amdgcn_mfma_f32_16x16x32_bf16(A.v, B.v, g0, 0, 0, 0);
      }
      // odd iteration (kt+1 == 31 masks q >= 2)
      {
        int kt1 = kt + 1;
        int k0 = kt1 * 32 + q * 8;
        union { s8 v; unsigned short u[8]; } A, B;
        if (kt1 < 31 || q < 2) {
          f4 a0v = *reinterpret_cast<const f4*>(arow + k0);
          f4 a1v = *reinterpret_cast<const f4*>(arow + k0 + 4);
          f4 b0v = *reinterpret_cast<const f4*>(brow + k0);
          f4 b1v = *reinterpret_cast<const f4*>(brow + k0 + 4);
          #pragma unroll
          for (int e = 0; e < 4; e++) {
            A.u[e] = bf16u(a0v[e]); A.u[4 + e] = bf16u(a1v[e]);
            B.u[e] = bf16u(b0v[e]); B.u[4 + e] = bf16u(b1v[e]);
          }
        } else {
          #pragma unroll
          for (int e = 0; e < 8; e++) { A.u[e] = 0; B.u[e] = 0; }
        }
        g1 = __builtin_amdgcn_mfma_f32_16x16x32_bf16(A.v, B.v, g1, 0, 0, 0);
      }
    }
    #pragma unroll
    for (int reg = 0; reg < 4; reg++)
      sm.g.G[mat][(mt * 16 + q * 4 + reg) * 16 + r] = g0[reg] + g1[reg];
    __syncthreads();
    for (int e = t; e < 1024; e += 256) {
      int j = e >> 4, i = e & 15;
      float eg2 = 0.f, eg3 = 0.f;
      #pragma unroll
      for (int cat = 0; cat < 32; cat++) {
        float ev = sm.g.embT[cat * 65 + j];
        eg2 = fmaf(ev, sm.g.G[0][cat * 16 + i], eg2);
        eg3 = fmaf(ev, sm.g.G[1][cat * 16 + i], eg3);
      }
      sm.g.EG2[e] = eg2; sm.g.EG3[e] = eg3;
    }
    __syncthreads();
    #pragma unroll
    for (int l = 0; l < 3; l++) {
      for (int e = t; e < 512; e += 256) {
        int cat = e >> 4, i = e & 15;
        float acc = 0.f;
        for (int j = 0; j < 64; j++) {
          float Al = sm.g.alphaC[l * 64 + j];
          float a0 = sm.g.alphaC[j];
          float u = Al * sm.g.EG2[j * 16 + i] - a0 * sm.g.EG3[j * 16 + i];
          acc = fmaf(sm.g.embT[cat * 65 + j], u, acc);
        }
        VBase[(size_t)b * 1536 + l * 512 + e] = acc;
      }
    }
  } else if (blockIdx.x < 1056) {
    int a = blockIdx.x - 32;
    int b = a >> 5;
    int ct = a & 31;
    int n0 = ct * 32;
    const float* xb = x + (size_t)b * DINR * NN;
    for (int idx = t; idx < 96 * 32; idx += 256) {
      int row = idx >> 5, col = idx & 31;
      sm.d.xs[row * 33 + col] = xb[(48 + row) * NN + n0 + col];
    }
    for (int e = t; e < 1024; e += 256) {
      int j = e >> 4, hp = e & 15;
      float f0 = emb[j * 32 + hp * 2];
      float f1 = emb[j * 32 + hp * 2 + 1];
      sm.d.Eb[j * 16 + hp] =
          (unsigned int)bf16u(f0) | ((unsigned int)bf16u(f1) << 16);
    }
    for (int e = t; e < 2048; e += 256) {
      int j = e >> 5, cat = e & 31;
      sm.d.etr[cat * 72 + j] = bf16u(emb[e]);
    }
    __syncthreads();
    int lane = t & 63, w = t >> 6;
    int r = lane & 15, q = lane >> 4;
    // B0 = E @ x3 (x3 = local rows 0..32)
    {
      s8 af = *reinterpret_cast<const s8*>(&sm.d.Eb[(w * 16 + r) * 16 + q * 4]);
      #pragma unroll
      for (int nt = 0; nt < 2; nt++) {
        union { s8 v; unsigned short u[8]; } B;
        #pragma unroll
        for (int e = 0; e < 8; e++)
          B.u[e] = bf16u(sm.d.xs[(q * 8 + e) * 33 + nt * 16 + r]);
        f4 acc = {0.f, 0.f, 0.f, 0.f};
        acc = __builtin_amdgcn_mfma_f32_16x16x32_bf16(af, B.v, acc, 0, 0, 0);
        int n = n0 + nt * 16 + r;
        unsigned int p0 = (unsigned int)bf16u(acc[0]) | ((unsigned int)bf16u(acc[1]) << 16);
        unsigned int p1 = (unsigned int)bf16u(acc[2]) | ((unsigned int)bf16u(acc[3]) << 16);
        unsigned int* dst = reinterpret_cast<unsigned int*>(
            Bt + ((size_t)b * NN + n) * 64 + w * 16 + q * 4);
        dst[0] = p0; dst[1] = p1;
      }
    }
    // S0 = E^T @ C0 (C0 = local rows 32..96)
    {
      int mt = w & 1;
      int nt = w >> 1;
      f4 acc = {0.f, 0.f, 0.f, 0.f};
      #pragma unroll
      for (int kt = 0; kt < 2; kt++) {
        s8 ae = *reinterpret_cast<const s8*>(&sm.d.etr[(mt * 16 + r) * 72 + kt * 32 + q * 8]);
        union { s8 v; unsigned short u[8]; } Bx;
        #pragma unroll
        for (int e = 0; e < 8; e++)
          Bx.u[e] = bf16u(sm.d.xs[(32 + kt * 32 + q * 8 + e) * 33 + nt * 16 + r]);
        acc = __builtin_amdgcn_mfma_f32_16x16x32_bf16(ae, Bx.v, acc, 0, 0, 0);
      }
      #pragma unroll
      for (int reg = 0; reg < 4; reg++)
        S0[(size_t)b * 32 * NN + (size_t)(mt * 16 + q * 4 + reg) * NN + n0 + nt * 16 + r] = acc[reg];
    }
  } else {
    int a = blockIdx.x - 1056;
    int b = a >> 4;
    int mg = a & 15;
    const float* xb = x + (size_t)b * DINR * NN;
    // stage X^T bf16-pair packed, chunk-split: XTc[chunk][n*4 + dword]
    #pragma unroll
    for (int rep = 0; rep < 4; rep++) {
      int n = t + (rep << 8);
      unsigned int pk[8];
      #pragma unroll
      for (int h = 0; h < 8; h++) {
        unsigned int u0 = __float_as_uint(xb[(2*h) * NN + n]);
        unsigned int u1 = __float_as_uint(xb[(2*h+1) * NN + n]);
        pk[h] = (u0 >> 16) | (u1 & 0xFFFF0000u);
      }
      u4 lo = {pk[0], pk[1], pk[2], pk[3]};
      u4 hi = {pk[4], pk[5], pk[6], pk[7]};
      *reinterpret_cast<u4*>(&sm.XTc[0][n * 4]) = lo;
      *reinterpret_cast<u4*>(&sm.XTc[1][n * 4]) = hi;
    }
    __syncthreads();
    int w = t >> 6;
    int lane = t & 63;
    int r = lane & 15;
    int g = lane >> 4;
    int mt = mg * 64 + w * 16;
    s8 zero8 = {0,0,0,0,0,0,0,0};
    s8 afrag = zero8;
    if (g < 2) afrag = *reinterpret_cast<const s8*>(&sm.XTc[g][(mt + r) * 4]);
    float bestv[4];
    int besti[4];
    #pragma unroll
    for (int j = 0; j < 4; j++) { bestv[j] = -3.4e38f; besti[j] = 0x7FFFFFFF; }
    for (int nt = 0; nt < 63; nt++) {
      s8 bfrag = zero8;
      if (g < 2) bfrag = *reinterpret_cast<const s8*>(&sm.XTc[g][(nt*16 + r) * 4]);
      f4 acc = {0.f, 0.f, 0.f, 0.f};
      acc = __builtin_amdgcn_mfma_f32_16x16x32_bf16(afrag, bfrag, acc, 0, 0, 0);
      int n = nt * 16 + r;
      #pragma unroll
      for (int j = 0; j < 4; j++) {
        float v = acc[j];
        bool better = (v > bestv[j]) || (v == bestv[j] && n < besti[j]);
        if (better) { bestv[j] = v; besti[j] = n; }
      }
    }
    #pragma unroll
    for (int s = 1; s < 16; s <<= 1) {
      #pragma unroll
      for (int j = 0; j < 4; j++) {
        float ov = __shfl_xor(bestv[j], s, 64);
        int   oi = __shfl_xor(besti[j], s, 64);
        bool better = (ov > bestv[j]) || (ov == bestv[j] && oi < besti[j]);
        if (better) { bestv[j] = ov; besti[j] = oi; }
      }
    }
    if (r == 0) {
      #pragma unroll
      for (int j = 0; j < 4; j++)
        nstar[b * NN + mt + g * 4 + j] = besti[j];
    }
  }
}

// ---------------------------------------------------------------------------
// k_upd (unchanged from R21 — proven)
// ---------------------------------------------------------------------------
__global__ __launch_bounds__(256) void k_upd(
    const float* __restrict__ x, const float* __restrict__ emb,
    const float* __restrict__ kpp, const float* __restrict__ alphaN,
    const float* __restrict__ VBase, const float* __restrict__ S0,
    const int* __restrict__ nstar,
    const float* __restrict__ WpIn, float* __restrict__ W1sum,
    const unsigned short* __restrict__ Bin, unsigned short* __restrict__ Bout,
    float* __restrict__ WpOut, int l, float* __restrict__ out)
{
  __shared__ unsigned short Xt[64 * 24];   // X^T [col][i]
  __shared__ unsigned short Xb[16 * 72];   // X [i][col]
  __shared__ unsigned short Eb[64 * 40];   // E [j][cat]
  __shared__ unsigned short Et[32 * 72];   // E^T [cat][j]
  __shared__ unsigned short Vs[32 * 24];   // V bf16 [cat][i]
  __shared__ unsigned short Ps[64 * 40];   // p bf16 [col][cat]
  __shared__ unsigned short Wsh[64 * 72];  // w bf16 [j][col]
  __shared__ float Ups[64 * 18];           // alpha-scaled Up chunk [j][i]
  int t = threadIdx.x;
  int b = blockIdx.x >> 4;
  int mt = blockIdx.x & 15;
  int n0 = mt * 64;
  int lane = t & 63, w = t >> 6;
  int r = lane & 15, q = lane >> 4;
  const float* xb = x + (size_t)b * DINR * NN;
  int mcol = n0 + w * 16 + r;

  // ---- early B prefetch (independent of softmax) ----
  int nst = 0;
  unsigned int pc[8], pg[8];
  if (l != 2) {
    nst = nstar[b * NN + mcol];
    const unsigned int* BC = reinterpret_cast<const unsigned int*>(
        Bin + ((size_t)b * NN + mcol) * 64);
    const unsigned int* BG = reinterpret_cast<const unsigned int*>(
        Bin + ((size_t)b * NN + nst) * 64);
    #pragma unroll
    for (int jt = 0; jt < 4; jt++) {
      pc[jt * 2]     = BC[jt * 8 + q * 2];
      pc[jt * 2 + 1] = BC[jt * 8 + q * 2 + 1];
      pg[jt * 2]     = BG[jt * 8 + q * 2];
      pg[jt * 2 + 1] = BG[jt * 8 + q * 2 + 1];
    }
  }

  // ---- staging (X, E, E^T) ----
  for (int e = t; e < 1024; e += 256) {
    int i = e >> 6, col = e & 63;
    unsigned short v = bf16u(xb[i * NN + n0 + col]);
    Xb[i * 72 + col] = v;
    Xt[col * 24 + i] = v;
  }
  for (int e = t; e < 2048; e += 256) {
    int j = e >> 5, cat = e & 31;
    unsigned short v = bf16u(emb[e]);
    Eb[j * 40 + cat] = v;
    Et[cat * 72 + j] = v;
  }
  // ---- comb-lite: V ----
  for (int e = t; e < 512; e += 256) {
    float acc = VBase[(size_t)b * 1536 + l * 512 + e];
    if (l == 1) {
      const float* pw = WpIn + (size_t)b * 16 * 512 + e;
      float s1 = 0.f;
      #pragma unroll 8
      for (int ch = 0; ch < 16; ch++) s1 += pw[ch * 512];
      if (mt == 0) W1sum[(size_t)b * 512 + e] = s1;
      acc -= s1;
    } else if (l == 2) {
      acc -= W1sum[(size_t)b * 512 + e];
      const float* pw = WpIn + (size_t)b * 16 * 512 + e;
      float s2 = 0.f;
      #pragma unroll 8
      for (int ch = 0; ch < 16; ch++) s2 += pw[ch * 512];
      acc -= s2;
    }
    Vs[(e >> 4) * 24 + (e & 15)] = bf16u(acc);
  }
  __syncthreads();

  float sc = kpp[0] * (1.0f / 1008.0f);
  s8 zero8 = {0, 0, 0, 0, 0, 0, 0, 0};

  // ---- logits = S0 + sc*(V@X) ----
  f4 sacc[2];
  {
    s8 bx = zero8;
    if (q < 2) bx = *reinterpret_cast<const s8*>(&Xt[(w * 16 + r) * 24 + q * 8]);
    #pragma unroll
    for (int ct = 0; ct < 2; ct++) {
      s8 av = zero8;
      if (q < 2) av = *reinterpret_cast<const s8*>(&Vs[(ct * 16 + r) * 24 + q * 8]);
      f4 z = {0.f, 0.f, 0.f, 0.f};
      f4 mm = __builtin_amdgcn_mfma_f32_16x16x32_bf16(av, bx, z, 0, 0, 0);
      #pragma unroll
      for (int reg = 0; reg < 4; reg++) {
        int cat = ct * 16 + q * 4 + reg;
        sacc[ct][reg] = S0[(size_t)b * 32 * NN + (size_t)cat * NN + mcol] + sc * mm[reg];
      }
    }
  }
  // ---- softmax ----
  float p[2][4];
  float mx = -3.4e38f;
  #pragma unroll
  for (int ct = 0; ct < 2; ct++)
    #pragma unroll
    for (int reg = 0; reg < 4; reg++) mx = fmaxf(mx, sacc[ct][reg]);
  mx = fmaxf(mx, __shfl_xor(mx, 16, 64));
  mx = fmaxf(mx, __shfl_xor(mx, 32, 64));
  float ss = 0.f;
  #pragma unroll
  for (int ct = 0; ct < 2; ct++)
    #pragma unroll
    for (int reg = 0; reg < 4; reg++) {
      p[ct][reg] = __expf(sacc[ct][reg] - mx);
      ss += p[ct][reg];
    }
  ss += __shfl_xor(ss, 16, 64);
  ss += __shfl_xor(ss, 32, 64);
  float inv = 1.0f / ss;
  #pragma unroll
  for (int ct = 0; ct < 2; ct++)
    #pragma unroll
    for (int reg = 0; reg < 4; reg++) p[ct][reg] *= inv;

  if (l == 2) {
    float* lo = out + ((size_t)b * NN + mcol) * 32;
    float* po = lo + (size_t)NB * NN * 32;
    #pragma unroll
    for (int ct = 0; ct < 2; ct++) {
      f4 vl = {sacc[ct][0], sacc[ct][1], sacc[ct][2], sacc[ct][3]};
      f4 vp = {p[ct][0], p[ct][1], p[ct][2], p[ct][3]};
      *reinterpret_cast<f4*>(lo + ct * 16 + q * 4) = vl;
      *reinterpret_cast<f4*>(po + ct * 16 + q * 4) = vp;
    }
    return;
  }

  // ---- p -> Ps (wave-local) ----
  #pragma unroll
  for (int ct = 0; ct < 2; ct++) {
    unsigned int u0 = (unsigned int)bf16u(p[ct][0]) | ((unsigned int)bf16u(p[ct][1]) << 16);
    unsigned int u1 = (unsigned int)bf16u(p[ct][2]) | ((unsigned int)bf16u(p[ct][3]) << 16);
    unsigned int base = (w * 16 + r) * 40 + ct * 16 + q * 4;
    *reinterpret_cast<unsigned int*>(&Ps[base]) = u0;
    *reinterpret_cast<unsigned int*>(&Ps[base + 2]) = u1;
  }
  // ---- GEMM3: Ep = Eb @ Ps ----
  f4 eacc[4];
  {
    s8 bp = *reinterpret_cast<const s8*>(&Ps[(w * 16 + r) * 40 + q * 8]);
    #pragma unroll
    for (int jt = 0; jt < 4; jt++) {
      s8 ae = *reinterpret_cast<const s8*>(&Eb[(jt * 16 + r) * 40 + q * 8]);
      f4 z = {0.f, 0.f, 0.f, 0.f};
      eacc[jt] = __builtin_amdgcn_mfma_f32_16x16x32_bf16(ae, bp, z, 0, 0, 0);
    }
  }
  // ---- B update (bf16, col-major [n][64]), inputs prefetched ----
  float vv[4][4];
  {
    unsigned int* BO = reinterpret_cast<unsigned int*>(
        Bout + ((size_t)b * NN + mcol) * 64);
    const float invM = 1.0f / 1008.0f;
    #pragma unroll
    for (int jt = 0; jt < 4; jt++) {
      unsigned int c0 = pc[jt * 2], c1 = pc[jt * 2 + 1];
      unsigned int g0 = pg[jt * 2], g1 = pg[jt * 2 + 1];
      float bc[4] = { bfu2f(c0 & 0xFFFFu), bfu2f(c0 >> 16),
                      bfu2f(c1 & 0xFFFFu), bfu2f(c1 >> 16) };
      float bg[4] = { bfu2f(g0 & 0xFFFFu), bfu2f(g0 >> 16),
                      bfu2f(g1 & 0xFFFFu), bfu2f(g1 >> 16) };
      float vo[4];
      #pragma unroll
      for (int reg = 0; reg < 4; reg++) {
        vo[reg] = bc[reg] - bg[reg] * invM + eacc[jt][reg];
        vv[jt][reg] = vo[reg];
      }
      BO[jt * 8 + q * 2]     = (unsigned int)bf16u(vo[0]) | ((unsigned int)bf16u(vo[1]) << 16);
      BO[jt * 8 + q * 2 + 1] = (unsigned int)bf16u(vo[2]) | ((unsigned int)bf16u(vo[3]) << 16);
    }
  }
  // ---- w -> Wsh (masked) ----
  {
    bool live = (mcol < 1008);
    #pragma unroll
    for (int jt = 0; jt < 4; jt++)
      #pragma unroll
      for (int reg = 0; reg < 4; reg++)
        Wsh[(jt * 16 + q * 4 + reg) * 72 + (w * 16 + r)] =
            live ? bf16u(vv[jt][reg]) : (unsigned short)0;
  }
  __syncthreads();
  // ---- GEMM4: uacc = w @ X^T (wave w -> j-tile w) ----
  f4 uacc = {0.f, 0.f, 0.f, 0.f};
  #pragma unroll
  for (int kt = 0; kt < 2; kt++) {
    s8 aw = *reinterpret_cast<const s8*>(&Wsh[(w * 16 + r) * 72 + kt * 32 + q * 8]);
    s8 bxx = *reinterpret_cast<const s8*>(&Xb[r * 72 + kt * 32 + q * 8]);
    uacc = __builtin_amdgcn_mfma_f32_16x16x32_bf16(aw, bxx, uacc, 0, 0, 0);
  }
  // ---- stage alpha-scaled Up chunk ----
  #pragma unroll
  for (int reg = 0; reg < 4; reg++)
    Ups[(w * 16 + q * 4 + reg) * 18 + r] = alphaN[w * 16 + q * 4 + reg] * uacc[reg];
  __syncthreads();
  // ---- Wchunk = E^T @ (alphaN∘Up) (waves 0-1, cat tile = w) ----
  if (w < 2) {
    f4 wacc = {0.f, 0.f, 0.f, 0.f};
    #pragma unroll
    for (int kt = 0; kt < 2; kt++) {
      s8 ae = *reinterpret_cast<const s8*>(&Et[(w * 16 + r) * 72 + kt * 32 + q * 8]);
      union { s8 v; unsigned short u[8]; } Bu;
      #pragma unroll
      for (int e = 0; e < 8; e++)
        Bu.u[e] = bf16u(Ups[(kt * 32 + q * 8 + e) * 18 + r]);
      wacc = __builtin_amdgcn_mfma_f32_16x16x32_bf16(ae, Bu.v, wacc, 0, 0, 0);
    }
    float* wp = WpOut + ((size_t)(b * 16 + mt)) * 512;
    #pragma unroll
    for (int reg = 0; reg < 4; reg++)
      wp[(w * 16 + q * 4 + reg) * 16 + r] = wacc[reg];
  }
}

extern "C" void kernel_launch(void* const* d_in, const int* in_sizes, int n_in,
                              void* d_out, int out_size, void* d_ws, size_t ws_size,
                              hipStream_t stream)
{
  const float* x     = (const float*)d_in[0];
  const float* alpha = (const float*)d_in[1];
  const float* kp    = (const float*)d_in[2];
  const float* emb   = (const float*)d_in[3];
  float* ws = (float*)d_ws;
  unsigned short* B0u = (unsigned short*)(ws + OFF_B0);
  unsigned short* B1u = (unsigned short*)(ws + OFF_B1);
  float* S0   = ws + OFF_S0;
  float* VB   = ws + OFF_VB;
  float* WpA  = ws + OFF_WPA;
  float* WpB  = ws + OFF_WPB;
  float* W1s  = ws + OFF_W1S;
  int*   ns   = (int*)(ws + OFF_NS);
  float* out  = (float*)d_out;

  k_init<<<1568, 256, 0, stream>>>(x, emb, alpha, B0u, S0, VB, ns);
  // layer 0: B0->B1, writes WpA (alpha1-scaled W chunks)
  k_upd<<<512, 256, 0, stream>>>(x, emb, kp, alpha + 64, VB, S0, ns,
                                 WpA, W1s, B0u, B1u, WpA, 0, out);
  // layer 1: B1->B0, reads WpA (W1), writes W1sum + WpB (alpha2-scaled)
  k_upd<<<512, 256, 0, stream>>>(x, emb, kp, alpha + 128, VB, S0, ns,
                                 WpA, W1s, B1u, B0u, WpB, 1, out);
  // layer 2 (last): reads W1sum + WpB, writes out
  k_upd<<<512, 256, 0, stream>>>(x, emb, kp, alpha, VB, S0, ns,
                                 WpB, W1s, B0u, B1u, WpA, 2, out);
}

// Round 23
// 58.822 us; speedup vs baseline: 1.8169x; 1.0102x over previous
//
#include <hip/hip_runtime.h>
#include <hip/hip_bf16.h>

#define NB 32
#define NN 1024
#define DINR 144

typedef __attribute__((ext_vector_type(4))) float f4;
typedef __attribute__((ext_vector_type(8))) short s8;
typedef __attribute__((ext_vector_type(4))) unsigned int u4;

// ws float offsets
#define OFF_B0   (0u)                          // bf16 [32][1024][64]
#define OFF_B1   (1048576u)
#define OFF_S0   (2097152u)                    // bf16 [32][32][1024] (in 1MB slot)
#define OFF_VB   (3145728u)                    // f32 [32][3][512]
#define OFF_WPA  (3194880u)                    // f32 [32][16][512]
#define OFF_WPB  (3457024u)
#define OFF_W1S  (3719168u)                    // f32 [32][512]
#define OFF_NS   (3735552u)

static __device__ __forceinline__ unsigned short bf16u(float f) {
  __hip_bfloat16 h = __float2bfloat16(f);
  return *reinterpret_cast<unsigned short*>(&h);
}
static __device__ __forceinline__ float bfu2f(unsigned int u16) {
  unsigned int v = u16 << 16;
  return __uint_as_float(v);
}

// ---------------------------------------------------------------------------
// k_init (grid 1568):
//  blocks [0,32): per-batch Gram (MFMA, dual-acc K-loop) + EG + VBase (LDS)
//  blocks [32,1056): dense: B0 = E@x3 (bf16 col-major); S0 = E^T@x[80:144]
//    (S0 stored bf16)
//  blocks [1056,1568): nstar argmax; X^T chunk-split XTc[2][n][4];
//    staging via f4 vector loads (4 n per thread)
// ---------------------------------------------------------------------------
__global__ __launch_bounds__(256) void k_init(
    const float* __restrict__ x, const float* __restrict__ emb,
    const float* __restrict__ alpha,
    unsigned short* __restrict__ Bt, unsigned short* __restrict__ S0,
    float* __restrict__ VBase, int* __restrict__ nstar)
{
  __shared__ union {
    unsigned int XTc[2][4096];                 // 32768 B (argmax, chunk-split)
    struct {
      float xs[96 * 33];                       // 12672 B (rows 48..144)
      unsigned int Eb[64 * 16];                // 4096 B
      unsigned short etr[32 * 72];             // 4608 B
    } d;
    struct {
      float G[2][512];
      float EG2[1024];
      float EG3[1024];
      float embT[32 * 65];
      float alphaC[3 * 64];
    } g;
  } sm;
  int t = threadIdx.x;
  if (blockIdx.x < 32) {
    // ---- Gram + VBase, one block per batch ----
    int b = blockIdx.x;
    const float* xb = x + (size_t)b * DINR * NN;
    for (int e = t; e < 2048; e += 256) {
      int j = e >> 5, cat = e & 31;
      sm.g.embT[cat * 65 + j] = emb[e];
    }
    if (t < 64) {
      float a0 = alpha[t];
      float a1 = a0 + alpha[64 + t];
      float a2 = a1 + alpha[128 + t];
      sm.g.alphaC[t] = a0;
      sm.g.alphaC[64 + t] = a1;
      sm.g.alphaC[128 + t] = a2;
    }
    int lane = t & 63, w = t >> 6;
    int r = lane & 15, q = lane >> 4;
    int mat = w >> 1, mt = w & 1;
    const float* arow = xb + (size_t)(16 + mat * 32 + mt * 16 + r) * NN;
    const float* brow = xb + (size_t)r * NN;
    f4 g0 = {0.f, 0.f, 0.f, 0.f};
    f4 g1 = {0.f, 0.f, 0.f, 0.f};
    for (int kt = 0; kt < 32; kt += 2) {
      {
        int k0 = kt * 32 + q * 8;
        union { s8 v; unsigned short u[8]; } A, B;
        f4 a0v = *reinterpret_cast<const f4*>(arow + k0);
        f4 a1v = *reinterpret_cast<const f4*>(arow + k0 + 4);
        f4 b0v = *reinterpret_cast<const f4*>(brow + k0);
        f4 b1v = *reinterpret_cast<const f4*>(brow + k0 + 4);
        #pragma unroll
        for (int e = 0; e < 4; e++) {
          A.u[e] = bf16u(a0v[e]); A.u[4 + e] = bf16u(a1v[e]);
          B.u[e] = bf16u(b0v[e]); B.u[4 + e] = bf16u(b1v[e]);
        }
        g0 = __builtin_amdgcn_mfma_f32_16x16x32_bf16(A.v, B.v, g0, 0, 0, 0);
      }
      {
        int kt1 = kt + 1;
        int k0 = kt1 * 32 + q * 8;
        union { s8 v; unsigned short u[8]; } A, B;
        if (kt1 < 31 || q < 2) {
          f4 a0v = *reinterpret_cast<const f4*>(arow + k0);
          f4 a1v = *reinterpret_cast<const f4*>(arow + k0 + 4);
          f4 b0v = *reinterpret_cast<const f4*>(brow + k0);
          f4 b1v = *reinterpret_cast<const f4*>(brow + k0 + 4);
          #pragma unroll
          for (int e = 0; e < 4; e++) {
            A.u[e] = bf16u(a0v[e]); A.u[4 + e] = bf16u(a1v[e]);
            B.u[e] = bf16u(b0v[e]); B.u[4 + e] = bf16u(b1v[e]);
          }
        } else {
          #pragma unroll
          for (int e = 0; e < 8; e++) { A.u[e] = 0; B.u[e] = 0; }
        }
        g1 = __builtin_amdgcn_mfma_f32_16x16x32_bf16(A.v, B.v, g1, 0, 0, 0);
      }
    }
    #pragma unroll
    for (int reg = 0; reg < 4; reg++)
      sm.g.G[mat][(mt * 16 + q * 4 + reg) * 16 + r] = g0[reg] + g1[reg];
    __syncthreads();
    for (int e = t; e < 1024; e += 256) {
      int j = e >> 4, i = e & 15;
      float eg2 = 0.f, eg3 = 0.f;
      #pragma unroll
      for (int cat = 0; cat < 32; cat++) {
        float ev = sm.g.embT[cat * 65 + j];
        eg2 = fmaf(ev, sm.g.G[0][cat * 16 + i], eg2);
        eg3 = fmaf(ev, sm.g.G[1][cat * 16 + i], eg3);
      }
      sm.g.EG2[e] = eg2; sm.g.EG3[e] = eg3;
    }
    __syncthreads();
    #pragma unroll
    for (int l = 0; l < 3; l++) {
      for (int e = t; e < 512; e += 256) {
        int cat = e >> 4, i = e & 15;
        float acc = 0.f;
        for (int j = 0; j < 64; j++) {
          float Al = sm.g.alphaC[l * 64 + j];
          float a0 = sm.g.alphaC[j];
          float u = Al * sm.g.EG2[j * 16 + i] - a0 * sm.g.EG3[j * 16 + i];
          acc = fmaf(sm.g.embT[cat * 65 + j], u, acc);
        }
        VBase[(size_t)b * 1536 + l * 512 + e] = acc;
      }
    }
  } else if (blockIdx.x < 1056) {
    int a = blockIdx.x - 32;
    int b = a >> 5;
    int ct = a & 31;
    int n0 = ct * 32;
    const float* xb = x + (size_t)b * DINR * NN;
    for (int idx = t; idx < 96 * 32; idx += 256) {
      int row = idx >> 5, col = idx & 31;
      sm.d.xs[row * 33 + col] = xb[(48 + row) * NN + n0 + col];
    }
    for (int e = t; e < 1024; e += 256) {
      int j = e >> 4, hp = e & 15;
      float f0 = emb[j * 32 + hp * 2];
      float f1 = emb[j * 32 + hp * 2 + 1];
      sm.d.Eb[j * 16 + hp] =
          (unsigned int)bf16u(f0) | ((unsigned int)bf16u(f1) << 16);
    }
    for (int e = t; e < 2048; e += 256) {
      int j = e >> 5, cat = e & 31;
      sm.d.etr[cat * 72 + j] = bf16u(emb[e]);
    }
    __syncthreads();
    int lane = t & 63, w = t >> 6;
    int r = lane & 15, q = lane >> 4;
    // B0 = E @ x3 (x3 = local rows 0..32)
    {
      s8 af = *reinterpret_cast<const s8*>(&sm.d.Eb[(w * 16 + r) * 16 + q * 4]);
      #pragma unroll
      for (int nt = 0; nt < 2; nt++) {
        union { s8 v; unsigned short u[8]; } B;
        #pragma unroll
        for (int e = 0; e < 8; e++)
          B.u[e] = bf16u(sm.d.xs[(q * 8 + e) * 33 + nt * 16 + r]);
        f4 acc = {0.f, 0.f, 0.f, 0.f};
        acc = __builtin_amdgcn_mfma_f32_16x16x32_bf16(af, B.v, acc, 0, 0, 0);
        int n = n0 + nt * 16 + r;
        unsigned int p0 = (unsigned int)bf16u(acc[0]) | ((unsigned int)bf16u(acc[1]) << 16);
        unsigned int p1 = (unsigned int)bf16u(acc[2]) | ((unsigned int)bf16u(acc[3]) << 16);
        unsigned int* dst = reinterpret_cast<unsigned int*>(
            Bt + ((size_t)b * NN + n) * 64 + w * 16 + q * 4);
        dst[0] = p0; dst[1] = p1;
      }
    }
    // S0 = E^T @ C0 (C0 = local rows 32..96), stored bf16
    {
      int mt = w & 1;
      int nt = w >> 1;
      f4 acc = {0.f, 0.f, 0.f, 0.f};
      #pragma unroll
      for (int kt = 0; kt < 2; kt++) {
        s8 ae = *reinterpret_cast<const s8*>(&sm.d.etr[(mt * 16 + r) * 72 + kt * 32 + q * 8]);
        union { s8 v; unsigned short u[8]; } Bx;
        #pragma unroll
        for (int e = 0; e < 8; e++)
          Bx.u[e] = bf16u(sm.d.xs[(32 + kt * 32 + q * 8 + e) * 33 + nt * 16 + r]);
        acc = __builtin_amdgcn_mfma_f32_16x16x32_bf16(ae, Bx.v, acc, 0, 0, 0);
      }
      #pragma unroll
      for (int reg = 0; reg < 4; reg++)
        S0[(size_t)b * 32 * NN + (size_t)(mt * 16 + q * 4 + reg) * NN + n0 + nt * 16 + r] =
            bf16u(acc[reg]);
    }
  } else {
    int a = blockIdx.x - 1056;
    int b = a >> 4;
    int mg = a & 15;
    const float* xb = x + (size_t)b * DINR * NN;
    // stage X^T bf16-pair packed, chunk-split; f4 vector loads (4 n / thread)
    {
      int n4 = t * 4;
      unsigned int dw[8][4];
      #pragma unroll
      for (int h = 0; h < 8; h++) {
        f4 v0 = *reinterpret_cast<const f4*>(xb + (size_t)(2 * h) * NN + n4);
        f4 v1 = *reinterpret_cast<const f4*>(xb + (size_t)(2 * h + 1) * NN + n4);
        #pragma unroll
        for (int k = 0; k < 4; k++) {
          unsigned int u0 = __float_as_uint(v0[k]);
          unsigned int u1 = __float_as_uint(v1[k]);
          dw[h][k] = (u0 >> 16) | (u1 & 0xFFFF0000u);
        }
      }
      #pragma unroll
      for (int c = 0; c < 2; c++)
        #pragma unroll
        for (int k = 0; k < 4; k++) {
          u4 vv = {dw[c*4+0][k], dw[c*4+1][k], dw[c*4+2][k], dw[c*4+3][k]};
          *reinterpret_cast<u4*>(&sm.XTc[c][(n4 + k) * 4]) = vv;
        }
    }
    __syncthreads();
    int w = t >> 6;
    int lane = t & 63;
    int r = lane & 15;
    int g = lane >> 4;
    int mt = mg * 64 + w * 16;
    s8 zero8 = {0,0,0,0,0,0,0,0};
    s8 afrag = zero8;
    if (g < 2) afrag = *reinterpret_cast<const s8*>(&sm.XTc[g][(mt + r) * 4]);
    float bestv[4];
    int besti[4];
    #pragma unroll
    for (int j = 0; j < 4; j++) { bestv[j] = -3.4e38f; besti[j] = 0x7FFFFFFF; }
    for (int nt = 0; nt < 63; nt++) {
      s8 bfrag = zero8;
      if (g < 2) bfrag = *reinterpret_cast<const s8*>(&sm.XTc[g][(nt*16 + r) * 4]);
      f4 acc = {0.f, 0.f, 0.f, 0.f};
      acc = __builtin_amdgcn_mfma_f32_16x16x32_bf16(afrag, bfrag, acc, 0, 0, 0);
      int n = nt * 16 + r;
      #pragma unroll
      for (int j = 0; j < 4; j++) {
        float v = acc[j];
        bool better = (v > bestv[j]) || (v == bestv[j] && n < besti[j]);
        if (better) { bestv[j] = v; besti[j] = n; }
      }
    }
    #pragma unroll
    for (int s = 1; s < 16; s <<= 1) {
      #pragma unroll
      for (int j = 0; j < 4; j++) {
        float ov = __shfl_xor(bestv[j], s, 64);
        int   oi = __shfl_xor(besti[j], s, 64);
        bool better = (ov > bestv[j]) || (ov == bestv[j] && oi < besti[j]);
        if (better) { bestv[j] = ov; besti[j] = oi; }
      }
    }
    if (r == 0) {
      #pragma unroll
      for (int j = 0; j < 4; j++)
        nstar[b * NN + mt + g * 4 + j] = besti[j];
    }
  }
}

// ---------------------------------------------------------------------------
// k_upd (R22-proven; only S0 now bf16)
// ---------------------------------------------------------------------------
__global__ __launch_bounds__(256) void k_upd(
    const float* __restrict__ x, const float* __restrict__ emb,
    const float* __restrict__ kpp, const float* __restrict__ alphaN,
    const float* __restrict__ VBase, const unsigned short* __restrict__ S0,
    const int* __restrict__ nstar,
    const float* __restrict__ WpIn, float* __restrict__ W1sum,
    const unsigned short* __restrict__ Bin, unsigned short* __restrict__ Bout,
    float* __restrict__ WpOut, int l, float* __restrict__ out)
{
  __shared__ unsigned short Xt[64 * 24];   // X^T [col][i]
  __shared__ unsigned short Xb[16 * 72];   // X [i][col]
  __shared__ unsigned short Eb[64 * 40];   // E [j][cat]
  __shared__ unsigned short Et[32 * 72];   // E^T [cat][j]
  __shared__ unsigned short Vs[32 * 24];   // V bf16 [cat][i]
  __shared__ unsigned short Ps[64 * 40];   // p bf16 [col][cat]
  __shared__ unsigned short Wsh[64 * 72];  // w bf16 [j][col]
  __shared__ float Ups[64 * 18];           // alpha-scaled Up chunk [j][i]
  int t = threadIdx.x;
  int b = blockIdx.x >> 4;
  int mt = blockIdx.x & 15;
  int n0 = mt * 64;
  int lane = t & 63, w = t >> 6;
  int r = lane & 15, q = lane >> 4;
  const float* xb = x + (size_t)b * DINR * NN;
  int mcol = n0 + w * 16 + r;

  // ---- early B prefetch (independent of softmax) ----
  int nst = 0;
  unsigned int pc[8], pg[8];
  if (l != 2) {
    nst = nstar[b * NN + mcol];
    const unsigned int* BC = reinterpret_cast<const unsigned int*>(
        Bin + ((size_t)b * NN + mcol) * 64);
    const unsigned int* BG = reinterpret_cast<const unsigned int*>(
        Bin + ((size_t)b * NN + nst) * 64);
    #pragma unroll
    for (int jt = 0; jt < 4; jt++) {
      pc[jt * 2]     = BC[jt * 8 + q * 2];
      pc[jt * 2 + 1] = BC[jt * 8 + q * 2 + 1];
      pg[jt * 2]     = BG[jt * 8 + q * 2];
      pg[jt * 2 + 1] = BG[jt * 8 + q * 2 + 1];
    }
  }

  // ---- staging (X, E, E^T) ----
  for (int e = t; e < 1024; e += 256) {
    int i = e >> 6, col = e & 63;
    unsigned short v = bf16u(xb[i * NN + n0 + col]);
    Xb[i * 72 + col] = v;
    Xt[col * 24 + i] = v;
  }
  for (int e = t; e < 2048; e += 256) {
    int j = e >> 5, cat = e & 31;
    unsigned short v = bf16u(emb[e]);
    Eb[j * 40 + cat] = v;
    Et[cat * 72 + j] = v;
  }
  // ---- comb-lite: V ----
  for (int e = t; e < 512; e += 256) {
    float acc = VBase[(size_t)b * 1536 + l * 512 + e];
    if (l == 1) {
      const float* pw = WpIn + (size_t)b * 16 * 512 + e;
      float s1 = 0.f;
      #pragma unroll 8
      for (int ch = 0; ch < 16; ch++) s1 += pw[ch * 512];
      if (mt == 0) W1sum[(size_t)b * 512 + e] = s1;
      acc -= s1;
    } else if (l == 2) {
      acc -= W1sum[(size_t)b * 512 + e];
      const float* pw = WpIn + (size_t)b * 16 * 512 + e;
      float s2 = 0.f;
      #pragma unroll 8
      for (int ch = 0; ch < 16; ch++) s2 += pw[ch * 512];
      acc -= s2;
    }
    Vs[(e >> 4) * 24 + (e & 15)] = bf16u(acc);
  }
  __syncthreads();

  float sc = kpp[0] * (1.0f / 1008.0f);
  s8 zero8 = {0, 0, 0, 0, 0, 0, 0, 0};

  // ---- logits = S0 + sc*(V@X) ----
  f4 sacc[2];
  {
    s8 bx = zero8;
    if (q < 2) bx = *reinterpret_cast<const s8*>(&Xt[(w * 16 + r) * 24 + q * 8]);
    #pragma unroll
    for (int ct = 0; ct < 2; ct++) {
      s8 av = zero8;
      if (q < 2) av = *reinterpret_cast<const s8*>(&Vs[(ct * 16 + r) * 24 + q * 8]);
      f4 z = {0.f, 0.f, 0.f, 0.f};
      f4 mm = __builtin_amdgcn_mfma_f32_16x16x32_bf16(av, bx, z, 0, 0, 0);
      #pragma unroll
      for (int reg = 0; reg < 4; reg++) {
        int cat = ct * 16 + q * 4 + reg;
        sacc[ct][reg] = bfu2f(S0[(size_t)b * 32 * NN + (size_t)cat * NN + mcol])
                        + sc * mm[reg];
      }
    }
  }
  // ---- softmax ----
  float p[2][4];
  float mx = -3.4e38f;
  #pragma unroll
  for (int ct = 0; ct < 2; ct++)
    #pragma unroll
    for (int reg = 0; reg < 4; reg++) mx = fmaxf(mx, sacc[ct][reg]);
  mx = fmaxf(mx, __shfl_xor(mx, 16, 64));
  mx = fmaxf(mx, __shfl_xor(mx, 32, 64));
  float ss = 0.f;
  #pragma unroll
  for (int ct = 0; ct < 2; ct++)
    #pragma unroll
    for (int reg = 0; reg < 4; reg++) {
      p[ct][reg] = __expf(sacc[ct][reg] - mx);
      ss += p[ct][reg];
    }
  ss += __shfl_xor(ss, 16, 64);
  ss += __shfl_xor(ss, 32, 64);
  float inv = 1.0f / ss;
  #pragma unroll
  for (int ct = 0; ct < 2; ct++)
    #pragma unroll
    for (int reg = 0; reg < 4; reg++) p[ct][reg] *= inv;

  if (l == 2) {
    float* lo = out + ((size_t)b * NN + mcol) * 32;
    float* po = lo + (size_t)NB * NN * 32;
    #pragma unroll
    for (int ct = 0; ct < 2; ct++) {
      f4 vl = {sacc[ct][0], sacc[ct][1], sacc[ct][2], sacc[ct][3]};
      f4 vp = {p[ct][0], p[ct][1], p[ct][2], p[ct][3]};
      *reinterpret_cast<f4*>(lo + ct * 16 + q * 4) = vl;
      *reinterpret_cast<f4*>(po + ct * 16 + q * 4) = vp;
    }
    return;
  }

  // ---- p -> Ps (wave-local) ----
  #pragma unroll
  for (int ct = 0; ct < 2; ct++) {
    unsigned int u0 = (unsigned int)bf16u(p[ct][0]) | ((unsigned int)bf16u(p[ct][1]) << 16);
    unsigned int u1 = (unsigned int)bf16u(p[ct][2]) | ((unsigned int)bf16u(p[ct][3]) << 16);
    unsigned int base = (w * 16 + r) * 40 + ct * 16 + q * 4;
    *reinterpret_cast<unsigned int*>(&Ps[base]) = u0;
    *reinterpret_cast<unsigned int*>(&Ps[base + 2]) = u1;
  }
  // ---- GEMM3: Ep = Eb @ Ps ----
  f4 eacc[4];
  {
    s8 bp = *reinterpret_cast<const s8*>(&Ps[(w * 16 + r) * 40 + q * 8]);
    #pragma unroll
    for (int jt = 0; jt < 4; jt++) {
      s8 ae = *reinterpret_cast<const s8*>(&Eb[(jt * 16 + r) * 40 + q * 8]);
      f4 z = {0.f, 0.f, 0.f, 0.f};
      eacc[jt] = __builtin_amdgcn_mfma_f32_16x16x32_bf16(ae, bp, z, 0, 0, 0);
    }
  }
  // ---- B update (bf16, col-major [n][64]), inputs prefetched ----
  float vv[4][4];
  {
    unsigned int* BO = reinterpret_cast<unsigned int*>(
        Bout + ((size_t)b * NN + mcol) * 64);
    const float invM = 1.0f / 1008.0f;
    #pragma unroll
    for (int jt = 0; jt < 4; jt++) {
      unsigned int c0 = pc[jt * 2], c1 = pc[jt * 2 + 1];
      unsigned int g0 = pg[jt * 2], g1 = pg[jt * 2 + 1];
      float bc[4] = { bfu2f(c0 & 0xFFFFu), bfu2f(c0 >> 16),
                      bfu2f(c1 & 0xFFFFu), bfu2f(c1 >> 16) };
      float bg[4] = { bfu2f(g0 & 0xFFFFu), bfu2f(g0 >> 16),
                      bfu2f(g1 & 0xFFFFu), bfu2f(g1 >> 16) };
      float vo[4];
      #pragma unroll
      for (int reg = 0; reg < 4; reg++) {
        vo[reg] = bc[reg] - bg[reg] * invM + eacc[jt][reg];
        vv[jt][reg] = vo[reg];
      }
      BO[jt * 8 + q * 2]     = (unsigned int)bf16u(vo[0]) | ((unsigned int)bf16u(vo[1]) << 16);
      BO[jt * 8 + q * 2 + 1] = (unsigned int)bf16u(vo[2]) | ((unsigned int)bf16u(vo[3]) << 16);
    }
  }
  // ---- w -> Wsh (masked) ----
  {
    bool live = (mcol < 1008);
    #pragma unroll
    for (int jt = 0; jt < 4; jt++)
      #pragma unroll
      for (int reg = 0; reg < 4; reg++)
        Wsh[(jt * 16 + q * 4 + reg) * 72 + (w * 16 + r)] =
            live ? bf16u(vv[jt][reg]) : (unsigned short)0;
  }
  __syncthreads();
  // ---- GEMM4: uacc = w @ X^T (wave w -> j-tile w) ----
  f4 uacc = {0.f, 0.f, 0.f, 0.f};
  #pragma unroll
  for (int kt = 0; kt < 2; kt++) {
    s8 aw = *reinterpret_cast<const s8*>(&Wsh[(w * 16 + r) * 72 + kt * 32 + q * 8]);
    s8 bxx = *reinterpret_cast<const s8*>(&Xb[r * 72 + kt * 32 + q * 8]);
    uacc = __builtin_amdgcn_mfma_f32_16x16x32_bf16(aw, bxx, uacc, 0, 0, 0);
  }
  // ---- stage alpha-scaled Up chunk ----
  #pragma unroll
  for (int reg = 0; reg < 4; reg++)
    Ups[(w * 16 + q * 4 + reg) * 18 + r] = alphaN[w * 16 + q * 4 + reg] * uacc[reg];
  __syncthreads();
  // ---- Wchunk = E^T @ (alphaN∘Up) (waves 0-1, cat tile = w) ----
  if (w < 2) {
    f4 wacc = {0.f, 0.f, 0.f, 0.f};
    #pragma unroll
    for (int kt = 0; kt < 2; kt++) {
      s8 ae = *reinterpret_cast<const s8*>(&Et[(w * 16 + r) * 72 + kt * 32 + q * 8]);
      union { s8 v; unsigned short u[8]; } Bu;
      #pragma unroll
      for (int e = 0; e < 8; e++)
        Bu.u[e] = bf16u(Ups[(kt * 32 + q * 8 + e) * 18 + r]);
      wacc = __builtin_amdgcn_mfma_f32_16x16x32_bf16(ae, Bu.v, wacc, 0, 0, 0);
    }
    float* wp = WpOut + ((size_t)(b * 16 + mt)) * 512;
    #pragma unroll
    for (int reg = 0; reg < 4; reg++)
      wp[(w * 16 + q * 4 + reg) * 16 + r] = wacc[reg];
  }
}

extern "C" void kernel_launch(void* const* d_in, const int* in_sizes, int n_in,
                              void* d_out, int out_size, void* d_ws, size_t ws_size,
                              hipStream_t stream)
{
  const float* x     = (const float*)d_in[0];
  const float* alpha = (const float*)d_in[1];
  const float* kp    = (const float*)d_in[2];
  const float* emb   = (const float*)d_in[3];
  float* ws = (float*)d_ws;
  unsigned short* B0u = (unsigned short*)(ws + OFF_B0);
  unsigned short* B1u = (unsigned short*)(ws + OFF_B1);
  unsigned short* S0b = (unsigned short*)(ws + OFF_S0);
  float* VB   = ws + OFF_VB;
  float* WpA  = ws + OFF_WPA;
  float* WpB  = ws + OFF_WPB;
  float* W1s  = ws + OFF_W1S;
  int*   ns   = (int*)(ws + OFF_NS);
  float* out  = (float*)d_out;

  k_init<<<1568, 256, 0, stream>>>(x, emb, alpha, B0u, S0b, VB, ns);
  // layer 0: B0->B1, writes WpA (alpha1-scaled W chunks)
  k_upd<<<512, 256, 0, stream>>>(x, emb, kp, alpha + 64, VB, S0b, ns,
                                 WpA, W1s, B0u, B1u, WpA, 0, out);
  // layer 1: B1->B0, reads WpA (W1), writes W1sum + WpB (alpha2-scaled)
  k_upd<<<512, 256, 0, stream>>>(x, emb, kp, alpha + 128, VB, S0b, ns,
                                 WpA, W1s, B1u, B0u, WpB, 1, out);
  // layer 2 (last): reads W1sum + WpB, writes out
  k_upd<<<512, 256, 0, stream>>>(x, emb, kp, alpha, VB, S0b, ns,
                                 WpB, W1s, B0u, B1u, WpA, 2, out);
}